// Round 4
// baseline (1105.117 us; speedup 1.0000x reference)
//
#include <hip/hip_runtime.h>
#include <cstddef>

#define N_NODES 50000
#define N_EDGES 800000
#define N_GRAPHS 128
#define DIM 128
#define N_LAYERS 4
#define GN_EPS 1e-5f

// bucket-sort params
#define B_CHUNK 256        // chunk blocks
#define EPB 3125           // edges per chunk (256*3125 = 800000 exactly)
#define BUCKET_SHIFT 9
#define BUCKET_SIZE 512
#define NB 98              // ceil(50000/512)

typedef unsigned short ushort_t;
typedef __attribute__((ext_vector_type(8))) short frag8;
typedef __attribute__((ext_vector_type(4))) float f32x4;

__device__ inline float bfbits2f(unsigned hi16) { return __uint_as_float(hi16 << 16); }
__device__ inline ushort_t bf16rne(float v) {
    unsigned u = __float_as_uint(v);
    unsigned r = u + 0x7fff + ((u >> 16) & 1);
    return (ushort_t)(r >> 16);
}
__device__ inline void bf16split(float v, ushort_t& h, ushort_t& l) {
    ushort_t hi = bf16rne(v);
    float fh = __uint_as_float(((unsigned)hi) << 16);
    l = bf16rne(v - fh);
    h = hi;
}

// ---------------- graph boundaries from SORTED batch ----------------
__global__ __launch_bounds__(256) void graph_bounds(const int* __restrict__ batch, int* __restrict__ gstart) {
    int i = blockIdx.x * 256 + threadIdx.x;
    if (i >= N_NODES) return;
    int b = batch[i];
    if (i == 0) {
        for (int g = 0; g <= b; ++g) gstart[g] = 0;
    } else {
        int pb = batch[i - 1];
        for (int g = pb + 1; g <= b; ++g) gstart[g] = i;
    }
    if (i == N_NODES - 1) {
        for (int g = b + 1; g <= N_GRAPHS; ++g) gstart[g] = N_NODES;
    }
}

// ---------------- bucket CSR phase 1: per-(bucket,chunk) counts (LDS, no global atomics) ----
__global__ __launch_bounds__(256) void p1_count(const int* __restrict__ dst, int* __restrict__ cnts) {
    __shared__ int cnt[NB];
    int t = threadIdx.x, blk = blockIdx.x;
    for (int i = t; i < NB; i += 256) cnt[i] = 0;
    __syncthreads();
    int base = blk * EPB;
    for (int i = t; i < EPB; i += 256) atomicAdd(&cnt[dst[base + i] >> BUCKET_SHIFT], 1);
    __syncthreads();
    for (int i = t; i < NB; i += 256) cnts[i * B_CHUNK + blk] = cnt[i];
}

// ---------------- 3-phase scan (over NB*B_CHUNK = 25088) ----------------
__global__ __launch_bounds__(1024) void scan_local(const int* __restrict__ in, int* __restrict__ out,
                                                   int* __restrict__ bsum, int n) {
    __shared__ int wsum[16];
    int tid = threadIdx.x, lane = tid & 63, w = tid >> 6;
    int gi = blockIdx.x * 1024 + tid;
    int v = (gi < n) ? in[gi] : 0;
    int s = v;
    #pragma unroll
    for (int off = 1; off < 64; off <<= 1) {
        int t = __shfl_up(s, off, 64);
        if (lane >= off) s += t;
    }
    if (lane == 63) wsum[w] = s;
    __syncthreads();
    if (w == 0) {
        int ws = (lane < 16) ? wsum[lane] : 0;
        #pragma unroll
        for (int off = 1; off < 16; off <<= 1) {
            int t = __shfl_up(ws, off, 64);
            if (lane >= off) ws += t;
        }
        if (lane < 16) wsum[lane] = ws;
    }
    __syncthreads();
    int woff = (w > 0) ? wsum[w - 1] : 0;
    if (gi < n) out[gi] = woff + s - v;
    if (tid == 1023) bsum[blockIdx.x] = woff + s;
}

__global__ __launch_bounds__(64) void scan_block(int* __restrict__ bsum, int nb) {
    int lane = threadIdx.x;
    int v = (lane < nb) ? bsum[lane] : 0;
    int s = v;
    #pragma unroll
    for (int off = 1; off < 64; off <<= 1) {
        int t = __shfl_up(s, off, 64);
        if (lane >= off) s += t;
    }
    if (lane < nb) bsum[lane] = s - v;
}

__global__ __launch_bounds__(1024) void scan_add(int* __restrict__ out, const int* __restrict__ bsum, int n, int total) {
    int gi = blockIdx.x * 1024 + threadIdx.x;
    if (gi < n) out[gi] += bsum[blockIdx.x];
    if (blockIdx.x == 0 && threadIdx.x == 0) out[n] = total;
}

// ---------------- bucket CSR phase 3: place packed (dstfine<<16 | src) into bucket-major ebuf ----
__global__ __launch_bounds__(256) void p3_place(const int* __restrict__ src, const int* __restrict__ dst,
                                                const int* __restrict__ off, unsigned* __restrict__ ebuf) {
    __shared__ int cur[NB];
    int t = threadIdx.x, blk = blockIdx.x;
    for (int i = t; i < NB; i += 256) cur[i] = off[i * B_CHUNK + blk];
    __syncthreads();
    int base = blk * EPB;
    for (int i = t; i < EPB; i += 256) {
        int d = dst[base + i];
        int b = d >> BUCKET_SHIFT;
        int pos = atomicAdd(&cur[b], 1);
        ebuf[pos] = (unsigned)src[base + i] | ((unsigned)(d & (BUCKET_SIZE - 1)) << 16);
    }
}

// ---------------- bucket CSR phase 4: per-bucket counting sort -> eoff + csr ----------------
__global__ __launch_bounds__(512) void p4_csr(const unsigned* __restrict__ ebuf, const int* __restrict__ off,
                                              int* __restrict__ eoff, int* __restrict__ csr) {
    __shared__ int cnt[BUCKET_SIZE];
    __shared__ int wsum[8];
    int k = blockIdx.x, t = threadIdx.x;
    int bstart = off[k * B_CHUNK];
    int bend = off[(k + 1) * B_CHUNK];
    cnt[t] = 0;
    __syncthreads();
    for (int i = bstart + t; i < bend; i += 512) atomicAdd(&cnt[ebuf[i] >> 16], 1);
    __syncthreads();
    // exclusive scan of cnt[512]
    int lane = t & 63, w = t >> 6;
    int v = cnt[t], s = v;
    #pragma unroll
    for (int o = 1; o < 64; o <<= 1) {
        int tt = __shfl_up(s, o, 64);
        if (lane >= o) s += tt;
    }
    if (lane == 63) wsum[w] = s;
    __syncthreads();
    if (w == 0) {
        int ws = (lane < 8) ? wsum[lane] : 0;
        #pragma unroll
        for (int o = 1; o < 8; o <<= 1) {
            int tt = __shfl_up(ws, o, 64);
            if (lane >= o) ws += tt;
        }
        if (lane < 8) wsum[lane] = ws;
    }
    __syncthreads();
    int woff = (w > 0) ? wsum[w - 1] : 0;
    int excl = woff + s - v;
    int node = k * BUCKET_SIZE + t;
    if (node < N_NODES) eoff[node] = bstart + excl;
    __syncthreads();
    cnt[t] = excl;  // reuse as cursor
    __syncthreads();
    for (int i = bstart + t; i < bend; i += 512) {
        unsigned p = ebuf[i];
        int pos = atomicAdd(&cnt[p >> 16], 1);
        csr[bstart + pos] = (int)(p & 0xffffu);
    }
    if (k == NB - 1 && t == 0) eoff[N_NODES] = N_EDGES;
}

// ---------------- weight convert: fp32 W[k][n] -> bf16 hi/lo, TRANSPOSED [n][k] ----------------
__global__ __launch_bounds__(256) void convert_w(const float* __restrict__ w1, const float* __restrict__ w2,
                                                 ushort_t* __restrict__ hi, ushort_t* __restrict__ lo) {
    int idx = blockIdx.x * 256 + threadIdx.x;
    if (idx >= 8 * DIM * DIM) return;
    int mat = idx >> 14;
    int e = idx & 16383;
    int n = e >> 7, k = e & 127;
    int l = mat >> 1;
    const float* src = (mat & 1) ? (w2 + (size_t)l * DIM * DIM) : (w1 + (size_t)l * DIM * DIM);
    float v = src[k * DIM + n];
    ushort_t h, lw;
    bf16split(v, h, lw);
    hi[(size_t)mat * DIM * DIM + n * DIM + k] = h;
    lo[(size_t)mat * DIM * DIM + n * DIM + k] = lw;
}

// ---------------- x -> bf16 packed ----------------
__global__ __launch_bounds__(256) void convert_x(const float* __restrict__ x, unsigned* __restrict__ Hb) {
    int i = blockIdx.x * 256 + threadIdx.x;
    if (i >= N_NODES * 64) return;
    float a = x[2 * i], b = x[2 * i + 1];
    Hb[i] = (unsigned)bf16rne(a) | ((unsigned)bf16rne(b) << 16);
}

// ---------------- GIN aggregation on bf16 h: T = h + sum_{j->i} h_j ----------------
__global__ __launch_bounds__(256) void agg_bf16(const unsigned* __restrict__ h, const int* __restrict__ eoff,
                                                const int* __restrict__ csr, unsigned* __restrict__ T) {
    int wid = (blockIdx.x * 256 + threadIdx.x) >> 6;
    int lane = threadIdx.x & 63;
    if (wid >= N_NODES) return;
    int lo = eoff[wid], hi = eoff[wid + 1];
    unsigned v = h[(size_t)wid * 64 + lane];
    float a0 = bfbits2f(v & 0xffffu);
    float a1 = bfbits2f(v >> 16);
    int e = lo;
    for (; e + 3 < hi; e += 4) {
        int j0 = csr[e], j1 = csr[e + 1], j2 = csr[e + 2], j3 = csr[e + 3];
        unsigned v0 = h[(size_t)j0 * 64 + lane];
        unsigned v1 = h[(size_t)j1 * 64 + lane];
        unsigned v2 = h[(size_t)j2 * 64 + lane];
        unsigned v3 = h[(size_t)j3 * 64 + lane];
        a0 += bfbits2f(v0 & 0xffffu) + bfbits2f(v1 & 0xffffu) + bfbits2f(v2 & 0xffffu) + bfbits2f(v3 & 0xffffu);
        a1 += bfbits2f(v0 >> 16) + bfbits2f(v1 >> 16) + bfbits2f(v2 >> 16) + bfbits2f(v3 >> 16);
    }
    for (; e < hi; ++e) {
        unsigned v0 = h[(size_t)csr[e] * 64 + lane];
        a0 += bfbits2f(v0 & 0xffffu);
        a1 += bfbits2f(v0 >> 16);
    }
    T[(size_t)wid * 64 + lane] = (unsigned)bf16rne(a0) | ((unsigned)bf16rne(a1) << 16);
}

// ---------------- fused layer GEMM: Z = relu(relu(T@W1+b1)@W2+b2), + per-graph stats ----------------
// A 128x128 per block, 4 waves, XOR-swizzled LDS; Z1 round-trips through As in LDS.
// Epilogue accumulates per-graph sum(v), sum(v^2) into gstats via fp32 atomics (pre-zeroed).
__global__ __launch_bounds__(256) void mm_layer(const ushort_t* __restrict__ A,
                                                const ushort_t* __restrict__ W1h, const ushort_t* __restrict__ W1l,
                                                const ushort_t* __restrict__ W2h, const ushort_t* __restrict__ W2l,
                                                const float* __restrict__ b1, const float* __restrict__ b2,
                                                const int* __restrict__ batch,
                                                float* __restrict__ gstats, ushort_t* __restrict__ Zb) {
    __shared__ ushort_t As[128 * 128];
    __shared__ ushort_t Ws[128 * 128];
    int tid = threadIdx.x;
    int row0 = blockIdx.x * 128;
    int wave = tid >> 6, lane = tid & 63;
    int q = lane >> 4, mn = lane & 15;

    f32x4 acc[2][8];
    #pragma unroll
    for (int t = 0; t < 2; ++t)
        #pragma unroll
        for (int n = 0; n < 8; ++n) acc[t][n] = (f32x4)(0.f);

    // stage A
    #pragma unroll
    for (int i = 0; i < 8; ++i) {
        int c = tid + i * 256;
        int r = c >> 4, c8 = c & 15;
        uint4 v = make_uint4(0u, 0u, 0u, 0u);
        int gr = row0 + r;
        if (gr < N_NODES) v = *(const uint4*)(A + (size_t)gr * DIM + c8 * 8);
        *(uint4*)(&As[r * 128 + (c8 ^ (r & 7)) * 8]) = v;
    }
    auto stageW = [&](const ushort_t* src) {
        #pragma unroll
        for (int i = 0; i < 8; ++i) {
            int c = tid + i * 256;
            int r = c >> 4, c8 = c & 15;
            uint4 v = *(const uint4*)(src + r * DIM + c8 * 8);
            *(uint4*)(&Ws[r * 128 + (c8 ^ (r & 7)) * 8]) = v;
        }
    };
    auto compute = [&]() {
        #pragma unroll
        for (int ks = 0; ks < 4; ++ks) {
            int m0 = wave * 32 + mn;
            int m1 = m0 + 16;
            frag8 a0 = *(const frag8*)&As[m0 * 128 + (((ks * 4 + q) ^ (m0 & 7)) * 8)];
            frag8 a1 = *(const frag8*)&As[m1 * 128 + (((ks * 4 + q) ^ (m1 & 7)) * 8)];
            #pragma unroll
            for (int n = 0; n < 8; ++n) {
                int nr = n * 16 + mn;
                frag8 b = *(const frag8*)&Ws[nr * 128 + (((ks * 4 + q) ^ (nr & 7)) * 8)];
                acc[0][n] = __builtin_amdgcn_mfma_f32_16x16x32_bf16(a0, b, acc[0][n], 0, 0, 0);
                acc[1][n] = __builtin_amdgcn_mfma_f32_16x16x32_bf16(a1, b, acc[1][n], 0, 0, 0);
            }
        }
    };

    // ---- GEMM 1: Z1 = relu(A@W1 + b1) ----
    stageW(W1h);
    __syncthreads(); compute(); __syncthreads();
    stageW(W1l);
    __syncthreads(); compute(); __syncthreads();

    // epilogue 1: write bf16 Z1 back into As (swizzled), reset acc
    int mloc = wave * 32;
    #pragma unroll
    for (int t = 0; t < 2; ++t) {
        #pragma unroll
        for (int n = 0; n < 8; ++n) {
            int col = n * 16 + mn;
            float bv = b1[col];
            #pragma unroll
            for (int r = 0; r < 4; ++r) {
                int rloc = mloc + t * 16 + q * 4 + r;
                float v = fmaxf(acc[t][n][r] + bv, 0.f);
                As[rloc * 128 + ((col >> 3) ^ (rloc & 7)) * 8 + (col & 7)] = bf16rne(v);
                acc[t][n][r] = 0.f;
            }
        }
    }
    // stage W2h (Ws free after sync)
    __syncthreads();
    stageW(W2h);
    __syncthreads(); compute(); __syncthreads();
    stageW(W2l);
    __syncthreads(); compute();

    // epilogue 2: v = relu(acc + b2), stats atomics + bf16 store
    #pragma unroll
    for (int t = 0; t < 2; ++t) {
        #pragma unroll
        for (int r = 0; r < 4; ++r) {
            int grow = row0 + mloc + t * 16 + q * 4 + r;
            if (grow >= N_NODES) continue;
            int g = batch[grow];
            float* s1 = gstats + (size_t)g * 128;
            float* s2 = gstats + 16384 + (size_t)g * 128;
            #pragma unroll
            for (int n = 0; n < 8; ++n) {
                int col = n * 16 + mn;
                float v = fmaxf(acc[t][n][r] + b2[col], 0.f);
                atomicAdd(&s1[col], v);
                atomicAdd(&s2[col], v * v);
                Zb[(size_t)grow * DIM + col] = bf16rne(v);
            }
        }
    }
}

// ---------------- GraphNorm apply (+relu, bf16 out) + optional readout; stats precomputed ----------
template<bool LAST>
__global__ __launch_bounds__(1024) void gn_apply(const ushort_t* __restrict__ Zb, const int* __restrict__ gstart,
                                                 const float* __restrict__ gstats,
                                                 const float* __restrict__ scale, const float* __restrict__ weight,
                                                 const float* __restrict__ bias,
                                                 ushort_t* __restrict__ Hb, float* __restrict__ gsum) {
    __shared__ float sa[128], sb[128];
    __shared__ float red[1024];
    int g = blockIdx.x;
    int t = threadIdx.x;
    int d = t & 127, rg = t >> 7;
    int s = gstart[g], e = gstart[g + 1];
    if (t < 128) {
        int cnt = e - s;
        float cf = (float)(cnt > 0 ? cnt : 1);
        float m = gstats[(size_t)g * 128 + t] / cf;
        float ez2 = gstats[16384 + (size_t)g * 128 + t] / cf;
        float sc = scale[t];
        float var = ez2 - (2.0f - sc) * sc * m * m;
        sa[t] = m * sc;
        sb[t] = weight[t] / sqrtf(var + GN_EPS);
    }
    __syncthreads();
    float asub = sa[d], bmul = sb[d], bi = bias[d];
    float rsum = 0.f;
    for (int n = s + rg; n < e; n += 8) {
        float z = bfbits2f(Zb[(size_t)n * DIM + d]);
        float o = fmaxf((z - asub) * bmul + bi, 0.f);
        if (LAST) rsum += o;
        else Hb[(size_t)n * DIM + d] = bf16rne(o);
    }
    if (LAST) {
        red[t] = rsum;
        __syncthreads();
        if (rg == 0) {
            #pragma unroll
            for (int k = 1; k < 8; ++k) rsum += red[d + 128 * k];
            gsum[g * DIM + d] = rsum;
        }
    }
}

// ---------------- final MLP + log_softmax ----------------
__global__ __launch_bounds__(128) void final_mlp(const float* __restrict__ gsum,
                                                 const float* __restrict__ fw1, const float* __restrict__ fb1,
                                                 const float* __restrict__ fw2, const float* __restrict__ fb2,
                                                 const float* __restrict__ fw3, const float* __restrict__ fb3,
                                                 float* __restrict__ out) {
    __shared__ float v0[128], v1[128], v2[128], lg[10];
    int t = threadIdx.x;
    int g = blockIdx.x;
    v0[t] = gsum[g * DIM + t];
    __syncthreads();
    float acc = fb1[t];
    for (int d = 0; d < 128; ++d) acc += v0[d] * fw1[d * 128 + t];
    v1[t] = fmaxf(acc, 0.f);
    __syncthreads();
    acc = fb2[t];
    for (int d = 0; d < 128; ++d) acc += v1[d] * fw2[d * 128 + t];
    v2[t] = fmaxf(acc, 0.f);
    __syncthreads();
    if (t < 10) {
        acc = fb3[t];
        for (int d = 0; d < 128; ++d) acc += v2[d] * fw3[d * 10 + t];
        lg[t] = acc;
    }
    __syncthreads();
    if (t < 10) {
        float m = -1e30f;
        for (int c = 0; c < 10; ++c) m = fmaxf(m, lg[c]);
        float ssum = 0.f;
        for (int c = 0; c < 10; ++c) ssum += expf(lg[c] - m);
        out[g * 10 + t] = lg[t] - m - logf(ssum);
    }
}

extern "C" void kernel_launch(void* const* d_in, const int* in_sizes, int n_in,
                              void* d_out, int out_size, void* d_ws, size_t ws_size,
                              hipStream_t stream) {
    const float* x      = (const float*)d_in[0];
    const float* gin_w1 = (const float*)d_in[1];
    const float* gin_b1 = (const float*)d_in[2];
    const float* gin_w2 = (const float*)d_in[3];
    const float* gin_b2 = (const float*)d_in[4];
    const float* gn_w   = (const float*)d_in[5];
    const float* gn_b   = (const float*)d_in[6];
    const float* gn_s   = (const float*)d_in[7];
    const float* fw1    = (const float*)d_in[8];
    const float* fb1    = (const float*)d_in[9];
    const float* fw2    = (const float*)d_in[10];
    const float* fb2    = (const float*)d_in[11];
    const float* fw3    = (const float*)d_in[12];
    const float* fb3    = (const float*)d_in[13];
    const int*   eidx   = (const int*)d_in[14];
    const int*   batch  = (const int*)d_in[15];
    float* out = (float*)d_out;

    const int* esrc = eidx;
    const int* edst = eidx + N_EDGES;

    auto align_up = [](size_t v) { return (v + 255) & ~(size_t)255; };
    char* p = (char*)d_ws;
    unsigned* Hb = (unsigned*)p;   p += align_up((size_t)N_NODES * DIM * 2);
    unsigned* Tb = (unsigned*)p;   p += align_up((size_t)N_NODES * DIM * 2);
    ushort_t* Zb = (ushort_t*)p;   p += align_up((size_t)N_NODES * DIM * 2);
    ushort_t* WThi = (ushort_t*)p; p += align_up((size_t)8 * DIM * DIM * 2);
    ushort_t* WTlo = (ushort_t*)p; p += align_up((size_t)8 * DIM * DIM * 2);
    float* gstats4 = (float*)p;    p += align_up((size_t)N_LAYERS * 2 * N_GRAPHS * DIM * 4);  // 512 KB
    float* gsum = (float*)p;       p += align_up(N_GRAPHS * DIM * 4);
    int* gstart = (int*)p;         p += align_up((N_GRAPHS + 1) * 4);
    int* cnts = (int*)p;           p += align_up((size_t)NB * B_CHUNK * 4);
    int* off = (int*)p;            p += align_up(((size_t)NB * B_CHUNK + 1) * 4);
    int* bsum = (int*)p;           p += align_up(64 * 4);
    unsigned* ebuf = (unsigned*)p; p += align_up((size_t)N_EDGES * 4);
    int* eoff = (int*)p;           p += align_up((N_NODES + 1) * 4);
    int* csr = (int*)p;            p += align_up((size_t)N_EDGES * 4);

    // zero the per-layer graph stats (the only buffer needing init)
    hipMemsetAsync(gstats4, 0, (size_t)N_LAYERS * 2 * N_GRAPHS * DIM * 4, stream);

    const int SCAN_N = NB * B_CHUNK;                      // 25088
    const int SCAN_BLKS = (SCAN_N + 1023) / 1024;         // 25
    graph_bounds<<<(N_NODES + 255) / 256, 256, 0, stream>>>(batch, gstart);
    p1_count<<<B_CHUNK, 256, 0, stream>>>(edst, cnts);
    scan_local<<<SCAN_BLKS, 1024, 0, stream>>>(cnts, off, bsum, SCAN_N);
    scan_block<<<1, 64, 0, stream>>>(bsum, SCAN_BLKS);
    scan_add<<<SCAN_BLKS, 1024, 0, stream>>>(off, bsum, SCAN_N, N_EDGES);
    p3_place<<<B_CHUNK, 256, 0, stream>>>(esrc, edst, off, ebuf);
    p4_csr<<<NB, 512, 0, stream>>>(ebuf, off, eoff, csr);
    convert_w<<<(8 * DIM * DIM + 255) / 256, 256, 0, stream>>>(gin_w1, gin_w2, WThi, WTlo);
    convert_x<<<(N_NODES * 64 + 255) / 256, 256, 0, stream>>>(x, Hb);

    const int mm_grid = (N_NODES + 127) / 128;
    for (int l = 0; l < N_LAYERS; ++l) {
        float* gstats = gstats4 + (size_t)l * 2 * N_GRAPHS * DIM;
        agg_bf16<<<(N_NODES + 3) / 4, 256, 0, stream>>>(Hb, eoff, csr, Tb);
        mm_layer<<<mm_grid, 256, 0, stream>>>((const ushort_t*)Tb,
            WThi + (size_t)(2 * l) * DIM * DIM, WTlo + (size_t)(2 * l) * DIM * DIM,
            WThi + (size_t)(2 * l + 1) * DIM * DIM, WTlo + (size_t)(2 * l + 1) * DIM * DIM,
            gin_b1 + l * DIM, gin_b2 + l * DIM, batch, gstats, Zb);
        if (l == N_LAYERS - 1)
            gn_apply<true><<<N_GRAPHS, 1024, 0, stream>>>(Zb, gstart, gstats, gn_s + l * DIM,
                gn_w + l * DIM, gn_b + l * DIM, (ushort_t*)Hb, gsum);
        else
            gn_apply<false><<<N_GRAPHS, 1024, 0, stream>>>(Zb, gstart, gstats, gn_s + l * DIM,
                gn_w + l * DIM, gn_b + l * DIM, (ushort_t*)Hb, gsum);
    }

    final_mlp<<<N_GRAPHS, 128, 0, stream>>>(gsum, fw1, fb1, fw2, fb2, fw3, fb3, out);
}

// Round 5
// 511.257 us; speedup vs baseline: 2.1616x; 2.1616x over previous
//
#include <hip/hip_runtime.h>
#include <cstddef>

#define N_NODES 50000
#define N_EDGES 800000
#define N_GRAPHS 128
#define DIM 128
#define N_LAYERS 4
#define GN_EPS 1e-5f

// bucket-sort params
#define B_CHUNK 256        // chunk blocks
#define EPB 3125           // edges per chunk (256*3125 = 800000 exactly)
#define BUCKET_SHIFT 9
#define BUCKET_SIZE 512
#define NB 98              // ceil(50000/512)

typedef unsigned short ushort_t;
typedef __attribute__((ext_vector_type(8))) short frag8;
typedef __attribute__((ext_vector_type(4))) float f32x4;

__device__ inline float bfbits2f(unsigned hi16) { return __uint_as_float(hi16 << 16); }
__device__ inline ushort_t bf16rne(float v) {
    unsigned u = __float_as_uint(v);
    unsigned r = u + 0x7fff + ((u >> 16) & 1);
    return (ushort_t)(r >> 16);
}
__device__ inline void bf16split(float v, ushort_t& h, ushort_t& l) {
    ushort_t hi = bf16rne(v);
    float fh = __uint_as_float(((unsigned)hi) << 16);
    l = bf16rne(v - fh);
    h = hi;
}

// ---------------- graph boundaries from SORTED batch ----------------
__global__ __launch_bounds__(256) void graph_bounds(const int* __restrict__ batch, int* __restrict__ gstart) {
    int i = blockIdx.x * 256 + threadIdx.x;
    if (i >= N_NODES) return;
    int b = batch[i];
    if (i == 0) {
        for (int g = 0; g <= b; ++g) gstart[g] = 0;
    } else {
        int pb = batch[i - 1];
        for (int g = pb + 1; g <= b; ++g) gstart[g] = i;
    }
    if (i == N_NODES - 1) {
        for (int g = b + 1; g <= N_GRAPHS; ++g) gstart[g] = N_NODES;
    }
}

// ---------------- bucket CSR phase 1: per-(bucket,chunk) counts (LDS, no global atomics) ----
__global__ __launch_bounds__(256) void p1_count(const int* __restrict__ dst, int* __restrict__ cnts) {
    __shared__ int cnt[NB];
    int t = threadIdx.x, blk = blockIdx.x;
    for (int i = t; i < NB; i += 256) cnt[i] = 0;
    __syncthreads();
    int base = blk * EPB;
    for (int i = t; i < EPB; i += 256) atomicAdd(&cnt[dst[base + i] >> BUCKET_SHIFT], 1);
    __syncthreads();
    for (int i = t; i < NB; i += 256) cnts[i * B_CHUNK + blk] = cnt[i];
}

// ---------------- 3-phase scan (over NB*B_CHUNK = 25088) ----------------
__global__ __launch_bounds__(1024) void scan_local(const int* __restrict__ in, int* __restrict__ out,
                                                   int* __restrict__ bsum, int n) {
    __shared__ int wsum[16];
    int tid = threadIdx.x, lane = tid & 63, w = tid >> 6;
    int gi = blockIdx.x * 1024 + tid;
    int v = (gi < n) ? in[gi] : 0;
    int s = v;
    #pragma unroll
    for (int off = 1; off < 64; off <<= 1) {
        int t = __shfl_up(s, off, 64);
        if (lane >= off) s += t;
    }
    if (lane == 63) wsum[w] = s;
    __syncthreads();
    if (w == 0) {
        int ws = (lane < 16) ? wsum[lane] : 0;
        #pragma unroll
        for (int off = 1; off < 16; off <<= 1) {
            int t = __shfl_up(ws, off, 64);
            if (lane >= off) ws += t;
        }
        if (lane < 16) wsum[lane] = ws;
    }
    __syncthreads();
    int woff = (w > 0) ? wsum[w - 1] : 0;
    if (gi < n) out[gi] = woff + s - v;
    if (tid == 1023) bsum[blockIdx.x] = woff + s;
}

__global__ __launch_bounds__(64) void scan_block(int* __restrict__ bsum, int nb) {
    int lane = threadIdx.x;
    int v = (lane < nb) ? bsum[lane] : 0;
    int s = v;
    #pragma unroll
    for (int off = 1; off < 64; off <<= 1) {
        int t = __shfl_up(s, off, 64);
        if (lane >= off) s += t;
    }
    if (lane < nb) bsum[lane] = s - v;
}

__global__ __launch_bounds__(1024) void scan_add(int* __restrict__ out, const int* __restrict__ bsum, int n, int total) {
    int gi = blockIdx.x * 1024 + threadIdx.x;
    if (gi < n) out[gi] += bsum[blockIdx.x];
    if (blockIdx.x == 0 && threadIdx.x == 0) out[n] = total;
}

// ---------------- bucket CSR phase 3: place packed (dstfine<<16 | src) into bucket-major ebuf ----
__global__ __launch_bounds__(256) void p3_place(const int* __restrict__ src, const int* __restrict__ dst,
                                                const int* __restrict__ off, unsigned* __restrict__ ebuf) {
    __shared__ int cur[NB];
    int t = threadIdx.x, blk = blockIdx.x;
    for (int i = t; i < NB; i += 256) cur[i] = off[i * B_CHUNK + blk];
    __syncthreads();
    int base = blk * EPB;
    for (int i = t; i < EPB; i += 256) {
        int d = dst[base + i];
        int b = d >> BUCKET_SHIFT;
        int pos = atomicAdd(&cur[b], 1);
        ebuf[pos] = (unsigned)src[base + i] | ((unsigned)(d & (BUCKET_SIZE - 1)) << 16);
    }
}

// ---------------- bucket CSR phase 4: per-bucket counting sort -> eoff + csr ----------------
__global__ __launch_bounds__(512) void p4_csr(const unsigned* __restrict__ ebuf, const int* __restrict__ off,
                                              int* __restrict__ eoff, int* __restrict__ csr) {
    __shared__ int cnt[BUCKET_SIZE];
    __shared__ int wsum[8];
    int k = blockIdx.x, t = threadIdx.x;
    int bstart = off[k * B_CHUNK];
    int bend = off[(k + 1) * B_CHUNK];
    cnt[t] = 0;
    __syncthreads();
    for (int i = bstart + t; i < bend; i += 512) atomicAdd(&cnt[ebuf[i] >> 16], 1);
    __syncthreads();
    int lane = t & 63, w = t >> 6;
    int v = cnt[t], s = v;
    #pragma unroll
    for (int o = 1; o < 64; o <<= 1) {
        int tt = __shfl_up(s, o, 64);
        if (lane >= o) s += tt;
    }
    if (lane == 63) wsum[w] = s;
    __syncthreads();
    if (w == 0) {
        int ws = (lane < 8) ? wsum[lane] : 0;
        #pragma unroll
        for (int o = 1; o < 8; o <<= 1) {
            int tt = __shfl_up(ws, o, 64);
            if (lane >= o) ws += tt;
        }
        if (lane < 8) wsum[lane] = ws;
    }
    __syncthreads();
    int woff = (w > 0) ? wsum[w - 1] : 0;
    int excl = woff + s - v;
    int node = k * BUCKET_SIZE + t;
    if (node < N_NODES) eoff[node] = bstart + excl;
    __syncthreads();
    cnt[t] = excl;  // reuse as cursor
    __syncthreads();
    for (int i = bstart + t; i < bend; i += 512) {
        unsigned p = ebuf[i];
        int pos = atomicAdd(&cnt[p >> 16], 1);
        csr[bstart + pos] = (int)(p & 0xffffu);
    }
    if (k == NB - 1 && t == 0) eoff[N_NODES] = N_EDGES;
}

// ---------------- weight convert: fp32 W[k][n] -> bf16 hi/lo, TRANSPOSED [n][k] ----------------
__global__ __launch_bounds__(256) void convert_w(const float* __restrict__ w1, const float* __restrict__ w2,
                                                 ushort_t* __restrict__ hi, ushort_t* __restrict__ lo) {
    int idx = blockIdx.x * 256 + threadIdx.x;
    if (idx >= 8 * DIM * DIM) return;
    int mat = idx >> 14;
    int e = idx & 16383;
    int n = e >> 7, k = e & 127;
    int l = mat >> 1;
    const float* src = (mat & 1) ? (w2 + (size_t)l * DIM * DIM) : (w1 + (size_t)l * DIM * DIM);
    float v = src[k * DIM + n];
    ushort_t h, lw;
    bf16split(v, h, lw);
    hi[(size_t)mat * DIM * DIM + n * DIM + k] = h;
    lo[(size_t)mat * DIM * DIM + n * DIM + k] = lw;
}

// ---------------- x -> bf16 packed ----------------
__global__ __launch_bounds__(256) void convert_x(const float* __restrict__ x, unsigned* __restrict__ Hb) {
    int i = blockIdx.x * 256 + threadIdx.x;
    if (i >= N_NODES * 64) return;
    float a = x[2 * i], b = x[2 * i + 1];
    Hb[i] = (unsigned)bf16rne(a) | ((unsigned)bf16rne(b) << 16);
}

// ---------------- GIN aggregation on bf16 h: T = h + sum_{j->i} h_j (8 outstanding gathers) ----
__global__ __launch_bounds__(256) void agg_bf16(const unsigned* __restrict__ h, const int* __restrict__ eoff,
                                                const int* __restrict__ csr, unsigned* __restrict__ T) {
    int wid = (blockIdx.x * 256 + threadIdx.x) >> 6;
    int lane = threadIdx.x & 63;
    if (wid >= N_NODES) return;
    int lo = eoff[wid], hi = eoff[wid + 1];
    unsigned v = h[(size_t)wid * 64 + lane];
    float a0 = bfbits2f(v & 0xffffu);
    float a1 = bfbits2f(v >> 16);
    int e = lo;
    for (; e + 7 < hi; e += 8) {
        unsigned w0 = h[(size_t)csr[e + 0] * 64 + lane];
        unsigned w1 = h[(size_t)csr[e + 1] * 64 + lane];
        unsigned w2 = h[(size_t)csr[e + 2] * 64 + lane];
        unsigned w3 = h[(size_t)csr[e + 3] * 64 + lane];
        unsigned w4 = h[(size_t)csr[e + 4] * 64 + lane];
        unsigned w5 = h[(size_t)csr[e + 5] * 64 + lane];
        unsigned w6 = h[(size_t)csr[e + 6] * 64 + lane];
        unsigned w7 = h[(size_t)csr[e + 7] * 64 + lane];
        a0 += bfbits2f(w0 & 0xffffu) + bfbits2f(w1 & 0xffffu) + bfbits2f(w2 & 0xffffu) + bfbits2f(w3 & 0xffffu)
            + bfbits2f(w4 & 0xffffu) + bfbits2f(w5 & 0xffffu) + bfbits2f(w6 & 0xffffu) + bfbits2f(w7 & 0xffffu);
        a1 += bfbits2f(w0 >> 16) + bfbits2f(w1 >> 16) + bfbits2f(w2 >> 16) + bfbits2f(w3 >> 16)
            + bfbits2f(w4 >> 16) + bfbits2f(w5 >> 16) + bfbits2f(w6 >> 16) + bfbits2f(w7 >> 16);
    }
    for (; e < hi; ++e) {
        unsigned v0 = h[(size_t)csr[e] * 64 + lane];
        a0 += bfbits2f(v0 & 0xffffu);
        a1 += bfbits2f(v0 >> 16);
    }
    T[(size_t)wid * 64 + lane] = (unsigned)bf16rne(a0) | ((unsigned)bf16rne(a1) << 16);
}

// ---------------- fused layer GEMM: Zf = relu(relu(T@W1+b1)@W2+b2), fp32 out, NO atomics ----------
// 128x128 per block, 4 waves, XOR-swizzled LDS; Z1 round-trips through As in LDS.
__global__ __launch_bounds__(256) void mm_layer(const ushort_t* __restrict__ A,
                                                const ushort_t* __restrict__ W1h, const ushort_t* __restrict__ W1l,
                                                const ushort_t* __restrict__ W2h, const ushort_t* __restrict__ W2l,
                                                const float* __restrict__ b1, const float* __restrict__ b2,
                                                float* __restrict__ Zf) {
    __shared__ ushort_t As[128 * 128];
    __shared__ ushort_t Ws[128 * 128];
    int tid = threadIdx.x;
    int row0 = blockIdx.x * 128;
    int wave = tid >> 6, lane = tid & 63;
    int q = lane >> 4, mn = lane & 15;

    f32x4 acc[2][8];
    #pragma unroll
    for (int t = 0; t < 2; ++t)
        #pragma unroll
        for (int n = 0; n < 8; ++n) acc[t][n] = (f32x4)(0.f);

    #pragma unroll
    for (int i = 0; i < 8; ++i) {
        int c = tid + i * 256;
        int r = c >> 4, c8 = c & 15;
        uint4 v = make_uint4(0u, 0u, 0u, 0u);
        int gr = row0 + r;
        if (gr < N_NODES) v = *(const uint4*)(A + (size_t)gr * DIM + c8 * 8);
        *(uint4*)(&As[r * 128 + (c8 ^ (r & 7)) * 8]) = v;
    }
    auto stageW = [&](const ushort_t* src) {
        #pragma unroll
        for (int i = 0; i < 8; ++i) {
            int c = tid + i * 256;
            int r = c >> 4, c8 = c & 15;
            uint4 v = *(const uint4*)(src + r * DIM + c8 * 8);
            *(uint4*)(&Ws[r * 128 + (c8 ^ (r & 7)) * 8]) = v;
        }
    };
    auto compute = [&]() {
        #pragma unroll
        for (int ks = 0; ks < 4; ++ks) {
            int m0 = wave * 32 + mn;
            int m1 = m0 + 16;
            frag8 a0 = *(const frag8*)&As[m0 * 128 + (((ks * 4 + q) ^ (m0 & 7)) * 8)];
            frag8 a1 = *(const frag8*)&As[m1 * 128 + (((ks * 4 + q) ^ (m1 & 7)) * 8)];
            #pragma unroll
            for (int n = 0; n < 8; ++n) {
                int nr = n * 16 + mn;
                frag8 b = *(const frag8*)&Ws[nr * 128 + (((ks * 4 + q) ^ (nr & 7)) * 8)];
                acc[0][n] = __builtin_amdgcn_mfma_f32_16x16x32_bf16(a0, b, acc[0][n], 0, 0, 0);
                acc[1][n] = __builtin_amdgcn_mfma_f32_16x16x32_bf16(a1, b, acc[1][n], 0, 0, 0);
            }
        }
    };

    // ---- GEMM 1: Z1 = relu(A@W1 + b1) ----
    stageW(W1h);
    __syncthreads(); compute(); __syncthreads();
    stageW(W1l);
    __syncthreads(); compute(); __syncthreads();

    // epilogue 1: write bf16 Z1 back into As (swizzled), reset acc
    int mloc = wave * 32;
    #pragma unroll
    for (int t = 0; t < 2; ++t) {
        #pragma unroll
        for (int n = 0; n < 8; ++n) {
            int col = n * 16 + mn;
            float bv = b1[col];
            #pragma unroll
            for (int r = 0; r < 4; ++r) {
                int rloc = mloc + t * 16 + q * 4 + r;
                float v = fmaxf(acc[t][n][r] + bv, 0.f);
                As[rloc * 128 + ((col >> 3) ^ (rloc & 7)) * 8 + (col & 7)] = bf16rne(v);
                acc[t][n][r] = 0.f;
            }
        }
    }
    __syncthreads();
    // ---- GEMM 2: Z = relu(Z1@W2 + b2) ----
    stageW(W2h);
    __syncthreads(); compute(); __syncthreads();
    stageW(W2l);
    __syncthreads(); compute();

    // epilogue 2: fp32 streaming store
    #pragma unroll
    for (int t = 0; t < 2; ++t) {
        #pragma unroll
        for (int n = 0; n < 8; ++n) {
            int col = n * 16 + mn;
            float bv = b2[col];
            #pragma unroll
            for (int r = 0; r < 4; ++r) {
                int grow = row0 + mloc + t * 16 + q * 4 + r;
                if (grow < N_NODES)
                    Zf[(size_t)grow * DIM + col] = fmaxf(acc[t][n][r] + bv, 0.f);
            }
        }
    }
}

// ---------------- fused GraphNorm: stats + apply(+relu, bf16 out) + optional readout ----------------
// var = E[z^2] - (2-s)*s*m^2  (since E[z] = m); one block per graph, 1024 threads
template<bool LAST>
__global__ __launch_bounds__(1024) void gn_fused(const float* __restrict__ Zf, const int* __restrict__ gstart,
                                                 const float* __restrict__ scale, const float* __restrict__ weight,
                                                 const float* __restrict__ bias,
                                                 ushort_t* __restrict__ Hb, float* __restrict__ gsum) {
    __shared__ float sh1[1024], sh2[1024];
    __shared__ float sa[128], sb[128];
    int g = blockIdx.x;
    int d = threadIdx.x & 127, rg = threadIdx.x >> 7;
    int s = gstart[g], e = gstart[g + 1];
    float s1 = 0.f, s2 = 0.f;
    for (int n = s + rg; n < e; n += 8) {
        float v = Zf[(size_t)n * DIM + d];
        s1 += v;
        s2 += v * v;
    }
    sh1[threadIdx.x] = s1;
    sh2[threadIdx.x] = s2;
    __syncthreads();
    if (rg == 0) {
        #pragma unroll
        for (int k = 1; k < 8; ++k) {
            s1 += sh1[d + 128 * k];
            s2 += sh2[d + 128 * k];
        }
        int cnt = e - s;
        float cf = (float)(cnt > 0 ? cnt : 1);
        float m = s1 / cf;
        float ez2 = s2 / cf;
        float sc = scale[d];
        float var = ez2 - (2.0f - sc) * sc * m * m;
        float inv = 1.0f / sqrtf(var + GN_EPS);
        sa[d] = m * sc;
        sb[d] = weight[d] * inv;
    }
    __syncthreads();
    float asub = sa[d], bmul = sb[d], bi = bias[d];
    float rsum = 0.f;
    for (int n = s + rg; n < e; n += 8) {
        float v = Zf[(size_t)n * DIM + d];
        float o = fmaxf((v - asub) * bmul + bi, 0.f);
        if (LAST) rsum += o;
        else Hb[(size_t)n * DIM + d] = bf16rne(o);
    }
    if (LAST) {
        __syncthreads();
        sh1[threadIdx.x] = rsum;
        __syncthreads();
        if (rg == 0) {
            #pragma unroll
            for (int k = 1; k < 8; ++k) rsum += sh1[d + 128 * k];
            gsum[g * DIM + d] = rsum;
        }
    }
}

// ---------------- final MLP + log_softmax ----------------
__global__ __launch_bounds__(128) void final_mlp(const float* __restrict__ gsum,
                                                 const float* __restrict__ fw1, const float* __restrict__ fb1,
                                                 const float* __restrict__ fw2, const float* __restrict__ fb2,
                                                 const float* __restrict__ fw3, const float* __restrict__ fb3,
                                                 float* __restrict__ out) {
    __shared__ float v0[128], v1[128], v2[128], lg[10];
    int t = threadIdx.x;
    int g = blockIdx.x;
    v0[t] = gsum[g * DIM + t];
    __syncthreads();
    float acc = fb1[t];
    for (int d = 0; d < 128; ++d) acc += v0[d] * fw1[d * 128 + t];
    v1[t] = fmaxf(acc, 0.f);
    __syncthreads();
    acc = fb2[t];
    for (int d = 0; d < 128; ++d) acc += v1[d] * fw2[d * 128 + t];
    v2[t] = fmaxf(acc, 0.f);
    __syncthreads();
    if (t < 10) {
        acc = fb3[t];
        for (int d = 0; d < 128; ++d) acc += v2[d] * fw3[d * 10 + t];
        lg[t] = acc;
    }
    __syncthreads();
    if (t < 10) {
        float m = -1e30f;
        for (int c = 0; c < 10; ++c) m = fmaxf(m, lg[c]);
        float ssum = 0.f;
        for (int c = 0; c < 10; ++c) ssum += expf(lg[c] - m);
        out[g * 10 + t] = lg[t] - m - logf(ssum);
    }
}

extern "C" void kernel_launch(void* const* d_in, const int* in_sizes, int n_in,
                              void* d_out, int out_size, void* d_ws, size_t ws_size,
                              hipStream_t stream) {
    const float* x      = (const float*)d_in[0];
    const float* gin_w1 = (const float*)d_in[1];
    const float* gin_b1 = (const float*)d_in[2];
    const float* gin_w2 = (const float*)d_in[3];
    const float* gin_b2 = (const float*)d_in[4];
    const float* gn_w   = (const float*)d_in[5];
    const float* gn_b   = (const float*)d_in[6];
    const float* gn_s   = (const float*)d_in[7];
    const float* fw1    = (const float*)d_in[8];
    const float* fb1    = (const float*)d_in[9];
    const float* fw2    = (const float*)d_in[10];
    const float* fb2    = (const float*)d_in[11];
    const float* fw3    = (const float*)d_in[12];
    const float* fb3    = (const float*)d_in[13];
    const int*   eidx   = (const int*)d_in[14];
    const int*   batch  = (const int*)d_in[15];
    float* out = (float*)d_out;

    const int* esrc = eidx;
    const int* edst = eidx + N_EDGES;

    auto align_up = [](size_t v) { return (v + 255) & ~(size_t)255; };
    char* p = (char*)d_ws;
    unsigned* Hb = (unsigned*)p;   p += align_up((size_t)N_NODES * DIM * 2);
    unsigned* Tb = (unsigned*)p;   p += align_up((size_t)N_NODES * DIM * 2);
    float* Zf = (float*)p;         p += align_up((size_t)N_NODES * DIM * 4);
    ushort_t* WThi = (ushort_t*)p; p += align_up((size_t)8 * DIM * DIM * 2);
    ushort_t* WTlo = (ushort_t*)p; p += align_up((size_t)8 * DIM * DIM * 2);
    float* gsum = (float*)p;       p += align_up(N_GRAPHS * DIM * 4);
    int* gstart = (int*)p;         p += align_up((N_GRAPHS + 1) * 4);
    int* cnts = (int*)p;           p += align_up((size_t)NB * B_CHUNK * 4);
    int* off = (int*)p;            p += align_up(((size_t)NB * B_CHUNK + 1) * 4);
    int* bsum = (int*)p;           p += align_up(64 * 4);
    unsigned* ebuf = (unsigned*)p; p += align_up((size_t)N_EDGES * 4);
    int* eoff = (int*)p;           p += align_up((N_NODES + 1) * 4);
    int* csr = (int*)p;            p += align_up((size_t)N_EDGES * 4);

    const int SCAN_N = NB * B_CHUNK;                      // 25088
    const int SCAN_BLKS = (SCAN_N + 1023) / 1024;         // 25
    graph_bounds<<<(N_NODES + 255) / 256, 256, 0, stream>>>(batch, gstart);
    p1_count<<<B_CHUNK, 256, 0, stream>>>(edst, cnts);
    scan_local<<<SCAN_BLKS, 1024, 0, stream>>>(cnts, off, bsum, SCAN_N);
    scan_block<<<1, 64, 0, stream>>>(bsum, SCAN_BLKS);
    scan_add<<<SCAN_BLKS, 1024, 0, stream>>>(off, bsum, SCAN_N, N_EDGES);
    p3_place<<<B_CHUNK, 256, 0, stream>>>(esrc, edst, off, ebuf);
    p4_csr<<<NB, 512, 0, stream>>>(ebuf, off, eoff, csr);
    convert_w<<<(8 * DIM * DIM + 255) / 256, 256, 0, stream>>>(gin_w1, gin_w2, WThi, WTlo);
    convert_x<<<(N_NODES * 64 + 255) / 256, 256, 0, stream>>>(x, Hb);

    const int mm_grid = (N_NODES + 127) / 128;
    for (int l = 0; l < N_LAYERS; ++l) {
        agg_bf16<<<(N_NODES + 3) / 4, 256, 0, stream>>>(Hb, eoff, csr, Tb);
        mm_layer<<<mm_grid, 256, 0, stream>>>((const ushort_t*)Tb,
            WThi + (size_t)(2 * l) * DIM * DIM, WTlo + (size_t)(2 * l) * DIM * DIM,
            WThi + (size_t)(2 * l + 1) * DIM * DIM, WTlo + (size_t)(2 * l + 1) * DIM * DIM,
            gin_b1 + l * DIM, gin_b2 + l * DIM, Zf);
        if (l == N_LAYERS - 1)
            gn_fused<true><<<N_GRAPHS, 1024, 0, stream>>>(Zf, gstart, gn_s + l * DIM,
                gn_w + l * DIM, gn_b + l * DIM, (ushort_t*)Hb, gsum);
        else
            gn_fused<false><<<N_GRAPHS, 1024, 0, stream>>>(Zf, gstart, gn_s + l * DIM,
                gn_w + l * DIM, gn_b + l * DIM, (ushort_t*)Hb, gsum);
    }

    final_mlp<<<N_GRAPHS, 128, 0, stream>>>(gsum, fw1, fb1, fw2, fb2, fw3, fb3, out);
}

// Round 6
// 442.966 us; speedup vs baseline: 2.4948x; 1.1542x over previous
//
#include <hip/hip_runtime.h>
#include <cstddef>

#define N_NODES 50000
#define N_EDGES 800000
#define N_GRAPHS 128
#define DIM 128
#define N_LAYERS 4
#define GN_EPS 1e-5f

// bucket-sort params
#define B_CHUNK 256        // chunk blocks
#define EPB 3125           // edges per chunk (256*3125 = 800000 exactly)
#define BUCKET_SHIFT 9
#define BUCKET_SIZE 512
#define NB 98              // ceil(50000/512)

typedef unsigned short ushort_t;
typedef __attribute__((ext_vector_type(8))) short frag8;
typedef __attribute__((ext_vector_type(4))) float f32x4;

__device__ inline float bfbits2f(unsigned hi16) { return __uint_as_float(hi16 << 16); }
__device__ inline ushort_t bf16rne(float v) {
    unsigned u = __float_as_uint(v);
    unsigned r = u + 0x7fff + ((u >> 16) & 1);
    return (ushort_t)(r >> 16);
}
__device__ inline unsigned packbf2(float a, float b) {
    return (unsigned)bf16rne(a) | ((unsigned)bf16rne(b) << 16);
}
__device__ inline void bf16split(float v, ushort_t& h, ushort_t& l) {
    ushort_t hi = bf16rne(v);
    float fh = __uint_as_float(((unsigned)hi) << 16);
    l = bf16rne(v - fh);
    h = hi;
}

// ---------------- graph boundaries from SORTED batch ----------------
__global__ __launch_bounds__(256) void graph_bounds(const int* __restrict__ batch, int* __restrict__ gstart) {
    int i = blockIdx.x * 256 + threadIdx.x;
    if (i >= N_NODES) return;
    int b = batch[i];
    if (i == 0) {
        for (int g = 0; g <= b; ++g) gstart[g] = 0;
    } else {
        int pb = batch[i - 1];
        for (int g = pb + 1; g <= b; ++g) gstart[g] = i;
    }
    if (i == N_NODES - 1) {
        for (int g = b + 1; g <= N_GRAPHS; ++g) gstart[g] = N_NODES;
    }
}

// ---------------- bucket CSR phase 1: per-(bucket,chunk) counts (LDS, no global atomics) ----
__global__ __launch_bounds__(256) void p1_count(const int* __restrict__ dst, int* __restrict__ cnts) {
    __shared__ int cnt[NB];
    int t = threadIdx.x, blk = blockIdx.x;
    for (int i = t; i < NB; i += 256) cnt[i] = 0;
    __syncthreads();
    int base = blk * EPB;
    for (int i = t; i < EPB; i += 256) atomicAdd(&cnt[dst[base + i] >> BUCKET_SHIFT], 1);
    __syncthreads();
    for (int i = t; i < NB; i += 256) cnts[i * B_CHUNK + blk] = cnt[i];
}

// ---------------- 3-phase scan (over NB*B_CHUNK = 25088) ----------------
__global__ __launch_bounds__(1024) void scan_local(const int* __restrict__ in, int* __restrict__ out,
                                                   int* __restrict__ bsum, int n) {
    __shared__ int wsum[16];
    int tid = threadIdx.x, lane = tid & 63, w = tid >> 6;
    int gi = blockIdx.x * 1024 + tid;
    int v = (gi < n) ? in[gi] : 0;
    int s = v;
    #pragma unroll
    for (int off = 1; off < 64; off <<= 1) {
        int t = __shfl_up(s, off, 64);
        if (lane >= off) s += t;
    }
    if (lane == 63) wsum[w] = s;
    __syncthreads();
    if (w == 0) {
        int ws = (lane < 16) ? wsum[lane] : 0;
        #pragma unroll
        for (int off = 1; off < 16; off <<= 1) {
            int t = __shfl_up(ws, off, 64);
            if (lane >= off) ws += t;
        }
        if (lane < 16) wsum[lane] = ws;
    }
    __syncthreads();
    int woff = (w > 0) ? wsum[w - 1] : 0;
    if (gi < n) out[gi] = woff + s - v;
    if (tid == 1023) bsum[blockIdx.x] = woff + s;
}

__global__ __launch_bounds__(64) void scan_block(int* __restrict__ bsum, int nb) {
    int lane = threadIdx.x;
    int v = (lane < nb) ? bsum[lane] : 0;
    int s = v;
    #pragma unroll
    for (int off = 1; off < 64; off <<= 1) {
        int t = __shfl_up(s, off, 64);
        if (lane >= off) s += t;
    }
    if (lane < nb) bsum[lane] = s - v;
}

__global__ __launch_bounds__(1024) void scan_add(int* __restrict__ out, const int* __restrict__ bsum, int n, int total) {
    int gi = blockIdx.x * 1024 + threadIdx.x;
    if (gi < n) out[gi] += bsum[blockIdx.x];
    if (blockIdx.x == 0 && threadIdx.x == 0) out[n] = total;
}

// ---------------- bucket CSR phase 3: place packed (dstfine<<16 | src) into bucket-major ebuf ----
__global__ __launch_bounds__(256) void p3_place(const int* __restrict__ src, const int* __restrict__ dst,
                                                const int* __restrict__ off, unsigned* __restrict__ ebuf) {
    __shared__ int cur[NB];
    int t = threadIdx.x, blk = blockIdx.x;
    for (int i = t; i < NB; i += 256) cur[i] = off[i * B_CHUNK + blk];
    __syncthreads();
    int base = blk * EPB;
    for (int i = t; i < EPB; i += 256) {
        int d = dst[base + i];
        int b = d >> BUCKET_SHIFT;
        int pos = atomicAdd(&cur[b], 1);
        ebuf[pos] = (unsigned)src[base + i] | ((unsigned)(d & (BUCKET_SIZE - 1)) << 16);
    }
}

// ---------------- bucket CSR phase 4: per-bucket counting sort -> eoff + csr ----------------
__global__ __launch_bounds__(512) void p4_csr(const unsigned* __restrict__ ebuf, const int* __restrict__ off,
                                              int* __restrict__ eoff, int* __restrict__ csr) {
    __shared__ int cnt[BUCKET_SIZE];
    __shared__ int wsum[8];
    int k = blockIdx.x, t = threadIdx.x;
    int bstart = off[k * B_CHUNK];
    int bend = off[(k + 1) * B_CHUNK];
    cnt[t] = 0;
    __syncthreads();
    for (int i = bstart + t; i < bend; i += 512) atomicAdd(&cnt[ebuf[i] >> 16], 1);
    __syncthreads();
    int lane = t & 63, w = t >> 6;
    int v = cnt[t], s = v;
    #pragma unroll
    for (int o = 1; o < 64; o <<= 1) {
        int tt = __shfl_up(s, o, 64);
        if (lane >= o) s += tt;
    }
    if (lane == 63) wsum[w] = s;
    __syncthreads();
    if (w == 0) {
        int ws = (lane < 8) ? wsum[lane] : 0;
        #pragma unroll
        for (int o = 1; o < 8; o <<= 1) {
            int tt = __shfl_up(ws, o, 64);
            if (lane >= o) ws += tt;
        }
        if (lane < 8) wsum[lane] = ws;
    }
    __syncthreads();
    int woff = (w > 0) ? wsum[w - 1] : 0;
    int excl = woff + s - v;
    int node = k * BUCKET_SIZE + t;
    if (node < N_NODES) eoff[node] = bstart + excl;
    __syncthreads();
    cnt[t] = excl;  // reuse as cursor
    __syncthreads();
    for (int i = bstart + t; i < bend; i += 512) {
        unsigned p = ebuf[i];
        int pos = atomicAdd(&cnt[p >> 16], 1);
        csr[bstart + pos] = (int)(p & 0xffffu);
    }
    if (k == NB - 1 && t == 0) eoff[N_NODES] = N_EDGES;
}

// ---------------- weight convert: fp32 W[k][n] -> bf16 hi/lo, TRANSPOSED [n][k] ----------------
__global__ __launch_bounds__(256) void convert_w(const float* __restrict__ w1, const float* __restrict__ w2,
                                                 ushort_t* __restrict__ hi, ushort_t* __restrict__ lo) {
    int idx = blockIdx.x * 256 + threadIdx.x;
    if (idx >= 8 * DIM * DIM) return;
    int mat = idx >> 14;
    int e = idx & 16383;
    int n = e >> 7, k = e & 127;
    int l = mat >> 1;
    const float* src = (mat & 1) ? (w2 + (size_t)l * DIM * DIM) : (w1 + (size_t)l * DIM * DIM);
    float v = src[k * DIM + n];
    ushort_t h, lw;
    bf16split(v, h, lw);
    hi[(size_t)mat * DIM * DIM + n * DIM + k] = h;
    lo[(size_t)mat * DIM * DIM + n * DIM + k] = lw;
}

// ---------------- x -> bf16 packed ----------------
__global__ __launch_bounds__(256) void convert_x(const float* __restrict__ x, unsigned* __restrict__ Hb) {
    int i = blockIdx.x * 256 + threadIdx.x;
    if (i >= N_NODES * 64) return;
    float a = x[2 * i], b = x[2 * i + 1];
    Hb[i] = packbf2(a, b);
}

// ---------------- GIN aggregation on bf16 h: T = h + sum_{j->i} h_j ----------------
// one wave per node; csr indices loaded ONCE lane-parallel (coalesced), broadcast via shfl;
// all gathers then stream with no interleaved uniform-load latency stage.
__global__ __launch_bounds__(256) void agg_bf16(const unsigned* __restrict__ h, const int* __restrict__ eoff,
                                                const int* __restrict__ csr, unsigned* __restrict__ T) {
    int wid = (blockIdx.x * 256 + threadIdx.x) >> 6;
    int lane = threadIdx.x & 63;
    if (wid >= N_NODES) return;
    int lo = eoff[wid], hi = eoff[wid + 1];
    unsigned v = h[(size_t)wid * 64 + lane];
    float a0 = bfbits2f(v & 0xffffu);
    float a1 = bfbits2f(v >> 16);
    for (int base = lo; base < hi; base += 64) {
        int nav = hi - base;
        if (nav > 64) nav = 64;
        int jv = (base + lane < hi) ? csr[base + lane] : 0;  // one coalesced load
        int e = 0;
        for (; e + 7 < nav; e += 8) {
            int j0 = __shfl(jv, e + 0, 64);
            int j1 = __shfl(jv, e + 1, 64);
            int j2 = __shfl(jv, e + 2, 64);
            int j3 = __shfl(jv, e + 3, 64);
            int j4 = __shfl(jv, e + 4, 64);
            int j5 = __shfl(jv, e + 5, 64);
            int j6 = __shfl(jv, e + 6, 64);
            int j7 = __shfl(jv, e + 7, 64);
            unsigned w0 = h[(size_t)j0 * 64 + lane];
            unsigned w1 = h[(size_t)j1 * 64 + lane];
            unsigned w2 = h[(size_t)j2 * 64 + lane];
            unsigned w3 = h[(size_t)j3 * 64 + lane];
            unsigned w4 = h[(size_t)j4 * 64 + lane];
            unsigned w5 = h[(size_t)j5 * 64 + lane];
            unsigned w6 = h[(size_t)j6 * 64 + lane];
            unsigned w7 = h[(size_t)j7 * 64 + lane];
            a0 += bfbits2f(w0 & 0xffffu) + bfbits2f(w1 & 0xffffu) + bfbits2f(w2 & 0xffffu) + bfbits2f(w3 & 0xffffu)
                + bfbits2f(w4 & 0xffffu) + bfbits2f(w5 & 0xffffu) + bfbits2f(w6 & 0xffffu) + bfbits2f(w7 & 0xffffu);
            a1 += bfbits2f(w0 >> 16) + bfbits2f(w1 >> 16) + bfbits2f(w2 >> 16) + bfbits2f(w3 >> 16)
                + bfbits2f(w4 >> 16) + bfbits2f(w5 >> 16) + bfbits2f(w6 >> 16) + bfbits2f(w7 >> 16);
        }
        for (; e < nav; ++e) {
            int j = __shfl(jv, e, 64);
            unsigned w0 = h[(size_t)j * 64 + lane];
            a0 += bfbits2f(w0 & 0xffffu);
            a1 += bfbits2f(w0 >> 16);
        }
    }
    T[(size_t)wid * 64 + lane] = packbf2(a0, a1);
}

// ---------------- fused layer GEMM: Zb = relu(relu(T@W1+b1)@W2+b2), bf16 out ----------
// 128x128 per block, 4 waves, XOR-swizzled LDS; Z1 round-trips through As in LDS.
__global__ __launch_bounds__(256) void mm_layer(const ushort_t* __restrict__ A,
                                                const ushort_t* __restrict__ W1h, const ushort_t* __restrict__ W1l,
                                                const ushort_t* __restrict__ W2h, const ushort_t* __restrict__ W2l,
                                                const float* __restrict__ b1, const float* __restrict__ b2,
                                                ushort_t* __restrict__ Zb) {
    __shared__ ushort_t As[128 * 128];
    __shared__ ushort_t Ws[128 * 128];
    int tid = threadIdx.x;
    int row0 = blockIdx.x * 128;
    int wave = tid >> 6, lane = tid & 63;
    int q = lane >> 4, mn = lane & 15;

    f32x4 acc[2][8];
    #pragma unroll
    for (int t = 0; t < 2; ++t)
        #pragma unroll
        for (int n = 0; n < 8; ++n) acc[t][n] = (f32x4)(0.f);

    #pragma unroll
    for (int i = 0; i < 8; ++i) {
        int c = tid + i * 256;
        int r = c >> 4, c8 = c & 15;
        uint4 v = make_uint4(0u, 0u, 0u, 0u);
        int gr = row0 + r;
        if (gr < N_NODES) v = *(const uint4*)(A + (size_t)gr * DIM + c8 * 8);
        *(uint4*)(&As[r * 128 + (c8 ^ (r & 7)) * 8]) = v;
    }
    auto stageW = [&](const ushort_t* src) {
        #pragma unroll
        for (int i = 0; i < 8; ++i) {
            int c = tid + i * 256;
            int r = c >> 4, c8 = c & 15;
            uint4 v = *(const uint4*)(src + r * DIM + c8 * 8);
            *(uint4*)(&Ws[r * 128 + (c8 ^ (r & 7)) * 8]) = v;
        }
    };
    auto compute = [&]() {
        #pragma unroll
        for (int ks = 0; ks < 4; ++ks) {
            int m0 = wave * 32 + mn;
            int m1 = m0 + 16;
            frag8 a0 = *(const frag8*)&As[m0 * 128 + (((ks * 4 + q) ^ (m0 & 7)) * 8)];
            frag8 a1 = *(const frag8*)&As[m1 * 128 + (((ks * 4 + q) ^ (m1 & 7)) * 8)];
            #pragma unroll
            for (int n = 0; n < 8; ++n) {
                int nr = n * 16 + mn;
                frag8 b = *(const frag8*)&Ws[nr * 128 + (((ks * 4 + q) ^ (nr & 7)) * 8)];
                acc[0][n] = __builtin_amdgcn_mfma_f32_16x16x32_bf16(a0, b, acc[0][n], 0, 0, 0);
                acc[1][n] = __builtin_amdgcn_mfma_f32_16x16x32_bf16(a1, b, acc[1][n], 0, 0, 0);
            }
        }
    };

    // ---- GEMM 1: Z1 = relu(A@W1 + b1) ----
    stageW(W1h);
    __syncthreads(); compute(); __syncthreads();
    stageW(W1l);
    __syncthreads(); compute(); __syncthreads();

    // epilogue 1: write bf16 Z1 back into As (swizzled), reset acc
    int mloc = wave * 32;
    #pragma unroll
    for (int t = 0; t < 2; ++t) {
        #pragma unroll
        for (int n = 0; n < 8; ++n) {
            int col = n * 16 + mn;
            float bv = b1[col];
            #pragma unroll
            for (int r = 0; r < 4; ++r) {
                int rloc = mloc + t * 16 + q * 4 + r;
                float v = fmaxf(acc[t][n][r] + bv, 0.f);
                As[rloc * 128 + ((col >> 3) ^ (rloc & 7)) * 8 + (col & 7)] = bf16rne(v);
                acc[t][n][r] = 0.f;
            }
        }
    }
    __syncthreads();
    // ---- GEMM 2: Z = relu(Z1@W2 + b2) ----
    stageW(W2h);
    __syncthreads(); compute(); __syncthreads();
    stageW(W2l);
    __syncthreads(); compute();

    // epilogue 2: bf16 streaming store
    #pragma unroll
    for (int t = 0; t < 2; ++t) {
        #pragma unroll
        for (int n = 0; n < 8; ++n) {
            int col = n * 16 + mn;
            float bv = b2[col];
            #pragma unroll
            for (int r = 0; r < 4; ++r) {
                int grow = row0 + mloc + t * 16 + q * 4 + r;
                if (grow < N_NODES)
                    Zb[(size_t)grow * DIM + col] = bf16rne(fmaxf(acc[t][n][r] + bv, 0.f));
            }
        }
    }
}

// ---------------- fused GraphNorm on bf16 Zb: stats + apply(+relu, bf16 out) + optional readout ----
// var = E[z^2] - (2-s)*s*m^2  (since E[z] = m); one block per graph, 1024 threads,
// packed-uint loads (2 dims/thread -> 256 B/wave coalescing)
template<bool LAST>
__global__ __launch_bounds__(1024) void gn_fused(const unsigned* __restrict__ Zb, const int* __restrict__ gstart,
                                                 const float* __restrict__ scale, const float* __restrict__ weight,
                                                 const float* __restrict__ bias,
                                                 unsigned* __restrict__ Hb, float* __restrict__ gsum) {
    __shared__ float2 sh1[1024], sh2[1024];
    __shared__ float sa[128], sb[128];
    int g = blockIdx.x;
    int dp = threadIdx.x & 63, rg = threadIdx.x >> 6;  // 16 row-groups x 64 dim-pairs
    int s = gstart[g], e = gstart[g + 1];
    float2 s1 = make_float2(0.f, 0.f), s2 = make_float2(0.f, 0.f);
    for (int n = s + rg; n < e; n += 16) {
        unsigned zz = Zb[(size_t)n * 64 + dp];
        float z0 = bfbits2f(zz & 0xffffu), z1 = bfbits2f(zz >> 16);
        s1.x += z0; s1.y += z1;
        s2.x += z0 * z0; s2.y += z1 * z1;
    }
    sh1[threadIdx.x] = s1;
    sh2[threadIdx.x] = s2;
    __syncthreads();
    if (rg == 0) {
        #pragma unroll
        for (int k = 1; k < 16; ++k) {
            float2 t1 = sh1[dp + 64 * k], t2 = sh2[dp + 64 * k];
            s1.x += t1.x; s1.y += t1.y;
            s2.x += t2.x; s2.y += t2.y;
        }
        int cnt = e - s;
        float cf = (float)(cnt > 0 ? cnt : 1);
        int d0 = dp * 2, d1 = d0 + 1;
        float m0 = s1.x / cf, m1 = s1.y / cf;
        float ez0 = s2.x / cf, ez1 = s2.y / cf;
        float sc0 = scale[d0], sc1 = scale[d1];
        float var0 = fmaxf(ez0 - (2.0f - sc0) * sc0 * m0 * m0, 0.f);
        float var1 = fmaxf(ez1 - (2.0f - sc1) * sc1 * m1 * m1, 0.f);
        sa[d0] = m0 * sc0;
        sa[d1] = m1 * sc1;
        sb[d0] = weight[d0] / sqrtf(var0 + GN_EPS);
        sb[d1] = weight[d1] / sqrtf(var1 + GN_EPS);
    }
    __syncthreads();
    int d0 = dp * 2, d1 = d0 + 1;
    float as0 = sa[d0], bm0 = sb[d0], bi0 = bias[d0];
    float as1 = sa[d1], bm1 = sb[d1], bi1 = bias[d1];
    float2 rsum = make_float2(0.f, 0.f);
    for (int n = s + rg; n < e; n += 16) {
        unsigned zz = Zb[(size_t)n * 64 + dp];
        float z0 = bfbits2f(zz & 0xffffu), z1 = bfbits2f(zz >> 16);
        float o0 = fmaxf((z0 - as0) * bm0 + bi0, 0.f);
        float o1 = fmaxf((z1 - as1) * bm1 + bi1, 0.f);
        if (LAST) {
            rsum.x += o0; rsum.y += o1;
        } else {
            Hb[(size_t)n * 64 + dp] = packbf2(o0, o1);
        }
    }
    if (LAST) {
        __syncthreads();
        sh1[threadIdx.x] = rsum;
        __syncthreads();
        if (rg == 0) {
            #pragma unroll
            for (int k = 1; k < 16; ++k) {
                float2 t1 = sh1[dp + 64 * k];
                rsum.x += t1.x; rsum.y += t1.y;
            }
            gsum[g * DIM + d0] = rsum.x;
            gsum[g * DIM + d1] = rsum.y;
        }
    }
}

// ---------------- final MLP + log_softmax ----------------
__global__ __launch_bounds__(128) void final_mlp(const float* __restrict__ gsum,
                                                 const float* __restrict__ fw1, const float* __restrict__ fb1,
                                                 const float* __restrict__ fw2, const float* __restrict__ fb2,
                                                 const float* __restrict__ fw3, const float* __restrict__ fb3,
                                                 float* __restrict__ out) {
    __shared__ float v0[128], v1[128], v2[128], lg[10];
    int t = threadIdx.x;
    int g = blockIdx.x;
    v0[t] = gsum[g * DIM + t];
    __syncthreads();
    float acc = fb1[t];
    for (int d = 0; d < 128; ++d) acc += v0[d] * fw1[d * 128 + t];
    v1[t] = fmaxf(acc, 0.f);
    __syncthreads();
    acc = fb2[t];
    for (int d = 0; d < 128; ++d) acc += v1[d] * fw2[d * 128 + t];
    v2[t] = fmaxf(acc, 0.f);
    __syncthreads();
    if (t < 10) {
        acc = fb3[t];
        for (int d = 0; d < 128; ++d) acc += v2[d] * fw3[d * 10 + t];
        lg[t] = acc;
    }
    __syncthreads();
    if (t < 10) {
        float m = -1e30f;
        for (int c = 0; c < 10; ++c) m = fmaxf(m, lg[c]);
        float ssum = 0.f;
        for (int c = 0; c < 10; ++c) ssum += expf(lg[c] - m);
        out[g * 10 + t] = lg[t] - m - logf(ssum);
    }
}

extern "C" void kernel_launch(void* const* d_in, const int* in_sizes, int n_in,
                              void* d_out, int out_size, void* d_ws, size_t ws_size,
                              hipStream_t stream) {
    const float* x      = (const float*)d_in[0];
    const float* gin_w1 = (const float*)d_in[1];
    const float* gin_b1 = (const float*)d_in[2];
    const float* gin_w2 = (const float*)d_in[3];
    const float* gin_b2 = (const float*)d_in[4];
    const float* gn_w   = (const float*)d_in[5];
    const float* gn_b   = (const float*)d_in[6];
    const float* gn_s   = (const float*)d_in[7];
    const float* fw1    = (const float*)d_in[8];
    const float* fb1    = (const float*)d_in[9];
    const float* fw2    = (const float*)d_in[10];
    const float* fb2    = (const float*)d_in[11];
    const float* fw3    = (const float*)d_in[12];
    const float* fb3    = (const float*)d_in[13];
    const int*   eidx   = (const int*)d_in[14];
    const int*   batch  = (const int*)d_in[15];
    float* out = (float*)d_out;

    const int* esrc = eidx;
    const int* edst = eidx + N_EDGES;

    auto align_up = [](size_t v) { return (v + 255) & ~(size_t)255; };
    char* p = (char*)d_ws;
    unsigned* Hb = (unsigned*)p;   p += align_up((size_t)N_NODES * DIM * 2);
    unsigned* Tb = (unsigned*)p;   p += align_up((size_t)N_NODES * DIM * 2);
    unsigned* Zb = (unsigned*)p;   p += align_up((size_t)N_NODES * DIM * 2);
    ushort_t* WThi = (ushort_t*)p; p += align_up((size_t)8 * DIM * DIM * 2);
    ushort_t* WTlo = (ushort_t*)p; p += align_up((size_t)8 * DIM * DIM * 2);
    float* gsum = (float*)p;       p += align_up(N_GRAPHS * DIM * 4);
    int* gstart = (int*)p;         p += align_up((N_GRAPHS + 1) * 4);
    int* cnts = (int*)p;           p += align_up((size_t)NB * B_CHUNK * 4);
    int* off = (int*)p;            p += align_up(((size_t)NB * B_CHUNK + 1) * 4);
    int* bsum = (int*)p;           p += align_up(64 * 4);
    unsigned* ebuf = (unsigned*)p; p += align_up((size_t)N_EDGES * 4);
    int* eoff = (int*)p;           p += align_up((N_NODES + 1) * 4);
    int* csr = (int*)p;            p += align_up((size_t)N_EDGES * 4);

    const int SCAN_N = NB * B_CHUNK;                      // 25088
    const int SCAN_BLKS = (SCAN_N + 1023) / 1024;         // 25
    graph_bounds<<<(N_NODES + 255) / 256, 256, 0, stream>>>(batch, gstart);
    p1_count<<<B_CHUNK, 256, 0, stream>>>(edst, cnts);
    scan_local<<<SCAN_BLKS, 1024, 0, stream>>>(cnts, off, bsum, SCAN_N);
    scan_block<<<1, 64, 0, stream>>>(bsum, SCAN_BLKS);
    scan_add<<<SCAN_BLKS, 1024, 0, stream>>>(off, bsum, SCAN_N, N_EDGES);
    p3_place<<<B_CHUNK, 256, 0, stream>>>(esrc, edst, off, ebuf);
    p4_csr<<<NB, 512, 0, stream>>>(ebuf, off, eoff, csr);
    convert_w<<<(8 * DIM * DIM + 255) / 256, 256, 0, stream>>>(gin_w1, gin_w2, WThi, WTlo);
    convert_x<<<(N_NODES * 64 + 255) / 256, 256, 0, stream>>>(x, Hb);

    const int mm_grid = (N_NODES + 127) / 128;
    for (int l = 0; l < N_LAYERS; ++l) {
        agg_bf16<<<(N_NODES + 3) / 4, 256, 0, stream>>>(Hb, eoff, csr, Tb);
        mm_layer<<<mm_grid, 256, 0, stream>>>((const ushort_t*)Tb,
            WThi + (size_t)(2 * l) * DIM * DIM, WTlo + (size_t)(2 * l) * DIM * DIM,
            WThi + (size_t)(2 * l + 1) * DIM * DIM, WTlo + (size_t)(2 * l + 1) * DIM * DIM,
            gin_b1 + l * DIM, gin_b2 + l * DIM, (ushort_t*)Zb);
        if (l == N_LAYERS - 1)
            gn_fused<true><<<N_GRAPHS, 1024, 0, stream>>>(Zb, gstart, gn_s + l * DIM,
                gn_w + l * DIM, gn_b + l * DIM, Hb, gsum);
        else
            gn_fused<false><<<N_GRAPHS, 1024, 0, stream>>>(Zb, gstart, gn_s + l * DIM,
                gn_w + l * DIM, gn_b + l * DIM, Hb, gsum);
    }

    final_mlp<<<N_GRAPHS, 128, 0, stream>>>(gsum, fw1, fb1, fw2, fb2, fw3, fb3, out);
}

// Round 8
// 427.869 us; speedup vs baseline: 2.5828x; 1.0353x over previous
//
#include <hip/hip_runtime.h>
#include <cstddef>

#define N_NODES 50000
#define N_EDGES 800000
#define N_GRAPHS 128
#define DIM 128
#define N_LAYERS 4
#define GN_EPS 1e-5f

// bucket-sort params
#define B_CHUNK 256        // chunk blocks
#define EPB 3125           // edges per chunk (256*3125 = 800000 exactly)
#define BUCKET_SHIFT 9
#define BUCKET_SIZE 512
#define NB 98              // ceil(50000/512)

// setup_misc grid partition
#define CX_BLKS 12500      // convert_x: 50000*64 uints / 256
#define CW_BLKS 512        // convert_w: 8*128*128 / 256
#define GB_BLKS 196        // graph_bounds: ceil(50000/256)
#define SETUP_BLKS (CX_BLKS + CW_BLKS + GB_BLKS + B_CHUNK)

typedef unsigned short ushort_t;
typedef __attribute__((ext_vector_type(8))) short frag8;
typedef __attribute__((ext_vector_type(4))) float f32x4;

__device__ inline float bfbits2f(unsigned hi16) { return __uint_as_float(hi16 << 16); }
__device__ inline ushort_t bf16rne(float v) {
    unsigned u = __float_as_uint(v);
    unsigned r = u + 0x7fff + ((u >> 16) & 1);
    return (ushort_t)(r >> 16);
}
__device__ inline unsigned packbf2(float a, float b) {
    return (unsigned)bf16rne(a) | ((unsigned)bf16rne(b) << 16);
}
__device__ inline void bf16split(float v, ushort_t& h, ushort_t& l) {
    ushort_t hi = bf16rne(v);
    float fh = __uint_as_float(((unsigned)hi) << 16);
    l = bf16rne(v - fh);
    h = hi;
}

// ---------------- merged independent setup: convert_x | convert_w | graph_bounds | p1_count ----
__global__ __launch_bounds__(256) void setup_misc(const float* __restrict__ x, unsigned* __restrict__ Hb,
                                                  const float* __restrict__ w1, const float* __restrict__ w2,
                                                  ushort_t* __restrict__ whi, ushort_t* __restrict__ wlo,
                                                  const int* __restrict__ batch, int* __restrict__ gstart,
                                                  const int* __restrict__ edst, int* __restrict__ cnts) {
    __shared__ int cnt[NB];
    int b = blockIdx.x, t = threadIdx.x;
    if (b < CX_BLKS) {
        int i = b * 256 + t;
        if (i < N_NODES * 64) {
            float a = x[2 * i], bb = x[2 * i + 1];
            Hb[i] = packbf2(a, bb);
        }
    } else if (b < CX_BLKS + CW_BLKS) {
        int idx = (b - CX_BLKS) * 256 + t;
        int mat = idx >> 14;
        int e = idx & 16383;
        int n = e >> 7, k = e & 127;
        int l = mat >> 1;
        const float* src = (mat & 1) ? (w2 + (size_t)l * DIM * DIM) : (w1 + (size_t)l * DIM * DIM);
        float v = src[k * DIM + n];
        ushort_t h, lw;
        bf16split(v, h, lw);
        whi[(size_t)mat * DIM * DIM + n * DIM + k] = h;
        wlo[(size_t)mat * DIM * DIM + n * DIM + k] = lw;
    } else if (b < CX_BLKS + CW_BLKS + GB_BLKS) {
        int i = (b - CX_BLKS - CW_BLKS) * 256 + t;
        if (i < N_NODES) {
            int bb = batch[i];
            if (i == 0) {
                for (int g = 0; g <= bb; ++g) gstart[g] = 0;
            } else {
                int pb = batch[i - 1];
                for (int g = pb + 1; g <= bb; ++g) gstart[g] = i;
            }
            if (i == N_NODES - 1) {
                for (int g = bb + 1; g <= N_GRAPHS; ++g) gstart[g] = N_NODES;
            }
        }
    } else {
        int blk = b - (CX_BLKS + CW_BLKS + GB_BLKS);
        for (int i = t; i < NB; i += 256) cnt[i] = 0;
        __syncthreads();
        int base = blk * EPB;
        for (int i = t; i < EPB; i += 256) atomicAdd(&cnt[edst[base + i] >> BUCKET_SHIFT], 1);
        __syncthreads();
        for (int i = t; i < NB; i += 256) cnts[i * B_CHUNK + blk] = cnt[i];
    }
}

// ---------------- 3-phase scan (over NB*B_CHUNK = 25088) ----------------
__global__ __launch_bounds__(1024) void scan_local(const int* __restrict__ in, int* __restrict__ out,
                                                   int* __restrict__ bsum, int n) {
    __shared__ int wsum[16];
    int tid = threadIdx.x, lane = tid & 63, w = tid >> 6;
    int gi = blockIdx.x * 1024 + tid;
    int v = (gi < n) ? in[gi] : 0;
    int s = v;
    #pragma unroll
    for (int off = 1; off < 64; off <<= 1) {
        int t = __shfl_up(s, off, 64);
        if (lane >= off) s += t;
    }
    if (lane == 63) wsum[w] = s;
    __syncthreads();
    if (w == 0) {
        int ws = (lane < 16) ? wsum[lane] : 0;
        #pragma unroll
        for (int off = 1; off < 16; off <<= 1) {
            int t = __shfl_up(ws, off, 64);
            if (lane >= off) ws += t;
        }
        if (lane < 16) wsum[lane] = ws;
    }
    __syncthreads();
    int woff = (w > 0) ? wsum[w - 1] : 0;
    if (gi < n) out[gi] = woff + s - v;
    if (tid == 1023) bsum[blockIdx.x] = woff + s;
}

__global__ __launch_bounds__(64) void scan_block(int* __restrict__ bsum, int nb) {
    int lane = threadIdx.x;
    int v = (lane < nb) ? bsum[lane] : 0;
    int s = v;
    #pragma unroll
    for (int off = 1; off < 64; off <<= 1) {
        int t = __shfl_up(s, off, 64);
        if (lane >= off) s += t;
    }
    if (lane < nb) bsum[lane] = s - v;
}

__global__ __launch_bounds__(1024) void scan_add(int* __restrict__ out, const int* __restrict__ bsum, int n, int total) {
    int gi = blockIdx.x * 1024 + threadIdx.x;
    if (gi < n) out[gi] += bsum[blockIdx.x];
    if (blockIdx.x == 0 && threadIdx.x == 0) out[n] = total;
}

// ---------------- bucket CSR phase 3: place packed (dstfine<<16 | src) into bucket-major ebuf ----
__global__ __launch_bounds__(256) void p3_place(const int* __restrict__ src, const int* __restrict__ dst,
                                                const int* __restrict__ off, unsigned* __restrict__ ebuf) {
    __shared__ int cur[NB];
    int t = threadIdx.x, blk = blockIdx.x;
    for (int i = t; i < NB; i += 256) cur[i] = off[i * B_CHUNK + blk];
    __syncthreads();
    int base = blk * EPB;
    for (int i = t; i < EPB; i += 256) {
        int d = dst[base + i];
        int b = d >> BUCKET_SHIFT;
        int pos = atomicAdd(&cur[b], 1);
        ebuf[pos] = (unsigned)src[base + i] | ((unsigned)(d & (BUCKET_SIZE - 1)) << 16);
    }
}

// ---------------- bucket CSR phase 4: per-bucket counting sort -> eoff + csr ----------------
__global__ __launch_bounds__(512) void p4_csr(const unsigned* __restrict__ ebuf, const int* __restrict__ off,
                                              int* __restrict__ eoff, int* __restrict__ csr) {
    __shared__ int cnt[BUCKET_SIZE];
    __shared__ int wsum[8];
    int k = blockIdx.x, t = threadIdx.x;
    int bstart = off[k * B_CHUNK];
    int bend = off[(k + 1) * B_CHUNK];
    cnt[t] = 0;
    __syncthreads();
    for (int i = bstart + t; i < bend; i += 512) atomicAdd(&cnt[ebuf[i] >> 16], 1);
    __syncthreads();
    int lane = t & 63, w = t >> 6;
    int v = cnt[t], s = v;
    #pragma unroll
    for (int o = 1; o < 64; o <<= 1) {
        int tt = __shfl_up(s, o, 64);
        if (lane >= o) s += tt;
    }
    if (lane == 63) wsum[w] = s;
    __syncthreads();
    if (w == 0) {
        int ws = (lane < 8) ? wsum[lane] : 0;
        #pragma unroll
        for (int o = 1; o < 8; o <<= 1) {
            int tt = __shfl_up(ws, o, 64);
            if (lane >= o) ws += tt;
        }
        if (lane < 8) wsum[lane] = ws;
    }
    __syncthreads();
    int woff = (w > 0) ? wsum[w - 1] : 0;
    int excl = woff + s - v;
    int node = k * BUCKET_SIZE + t;
    if (node < N_NODES) eoff[node] = bstart + excl;
    __syncthreads();
    cnt[t] = excl;  // reuse as cursor
    __syncthreads();
    for (int i = bstart + t; i < bend; i += 512) {
        unsigned p = ebuf[i];
        int pos = atomicAdd(&cnt[p >> 16], 1);
        csr[bstart + pos] = (int)(p & 0xffffu);
    }
    if (k == NB - 1 && t == 0) eoff[N_NODES] = N_EDGES;
}

// ---------------- GIN aggregation v3 (fixed): half-wave edge pairing, uint2 lanes ----------------
// one wave per node; halves process even/odd edges concurrently; UNIFORM trip counts across the
// wave (cmin fully-valid unrolled, cmax predicated tail) so every __shfl source lane is active.
__global__ __launch_bounds__(256) void agg_bf16(const uint2* __restrict__ h2, const int* __restrict__ eoff,
                                                const int* __restrict__ csr, uint2* __restrict__ T2) {
    int wid = (blockIdx.x * 256 + threadIdx.x) >> 6;
    int lane = threadIdx.x & 63;
    int half = lane >> 5;
    int hl = lane & 31;
    if (wid >= N_NODES) return;
    int lo = eoff[wid], hi = eoff[wid + 1];

    float a0 = 0.f, a1 = 0.f, a2 = 0.f, a3 = 0.f;
    if (half == 0) {
        uint2 sv = h2[(size_t)wid * 32 + hl];
        a0 = bfbits2f(sv.x & 0xffffu); a1 = bfbits2f(sv.x >> 16);
        a2 = bfbits2f(sv.y & 0xffffu); a3 = bfbits2f(sv.y >> 16);
    }

    for (int base = lo; base < hi; base += 64) {
        int nav = hi - base;
        if (nav > 64) nav = 64;
        int jv = (base + lane < hi) ? csr[base + lane] : 0;  // one coalesced index load
        int cmin = nav >> 1;         // iterations where BOTH halves have a valid edge
        int cmax = (nav + 1) >> 1;   // uniform loop bound for the whole wave
        int i = 0;
        for (; i + 3 < cmin; i += 4) {  // uniform bound; all 64 lanes active at every shfl
            int j0 = __shfl(jv, 2 * (i + 0) + half, 64);
            int j1 = __shfl(jv, 2 * (i + 1) + half, 64);
            int j2 = __shfl(jv, 2 * (i + 2) + half, 64);
            int j3 = __shfl(jv, 2 * (i + 3) + half, 64);
            uint2 w0 = h2[(size_t)j0 * 32 + hl];
            uint2 w1 = h2[(size_t)j1 * 32 + hl];
            uint2 w2 = h2[(size_t)j2 * 32 + hl];
            uint2 w3 = h2[(size_t)j3 * 32 + hl];
            a0 += bfbits2f(w0.x & 0xffffu) + bfbits2f(w1.x & 0xffffu) + bfbits2f(w2.x & 0xffffu) + bfbits2f(w3.x & 0xffffu);
            a1 += bfbits2f(w0.x >> 16) + bfbits2f(w1.x >> 16) + bfbits2f(w2.x >> 16) + bfbits2f(w3.x >> 16);
            a2 += bfbits2f(w0.y & 0xffffu) + bfbits2f(w1.y & 0xffffu) + bfbits2f(w2.y & 0xffffu) + bfbits2f(w3.y & 0xffffu);
            a3 += bfbits2f(w0.y >> 16) + bfbits2f(w1.y >> 16) + bfbits2f(w2.y >> 16) + bfbits2f(w3.y >> 16);
        }
        for (; i < cmax; ++i) {          // uniform bound; shfl BEFORE the predicate
            int epos = 2 * i + half;     // <= 63 always (nav <= 64)
            int j = __shfl(jv, epos, 64);
            if (epos < nav) {            // divergence only after the shfl — safe
                uint2 w0 = h2[(size_t)j * 32 + hl];
                a0 += bfbits2f(w0.x & 0xffffu); a1 += bfbits2f(w0.x >> 16);
                a2 += bfbits2f(w0.y & 0xffffu); a3 += bfbits2f(w0.y >> 16);
            }
        }
    }

    // cross-half combine: lanes 0-31 pick up lanes 32-63's partials (all lanes active here)
    a0 += __shfl_down(a0, 32, 64);
    a1 += __shfl_down(a1, 32, 64);
    a2 += __shfl_down(a2, 32, 64);
    a3 += __shfl_down(a3, 32, 64);
    if (half == 0) {
        uint2 o;
        o.x = packbf2(a0, a1);
        o.y = packbf2(a2, a3);
        T2[(size_t)wid * 32 + hl] = o;
    }
}

// ---------------- fused layer GEMM: Zb = relu(relu(T@W1+b1)@W2+b2), bf16 out ----------
// 128x128 per block, 4 waves, XOR-swizzled LDS; Z1 round-trips through As in LDS.
__global__ __launch_bounds__(256) void mm_layer(const ushort_t* __restrict__ A,
                                                const ushort_t* __restrict__ W1h, const ushort_t* __restrict__ W1l,
                                                const ushort_t* __restrict__ W2h, const ushort_t* __restrict__ W2l,
                                                const float* __restrict__ b1, const float* __restrict__ b2,
                                                ushort_t* __restrict__ Zb) {
    __shared__ ushort_t As[128 * 128];
    __shared__ ushort_t Ws[128 * 128];
    int tid = threadIdx.x;
    int row0 = blockIdx.x * 128;
    int wave = tid >> 6, lane = tid & 63;
    int q = lane >> 4, mn = lane & 15;

    f32x4 acc[2][8];
    #pragma unroll
    for (int t = 0; t < 2; ++t)
        #pragma unroll
        for (int n = 0; n < 8; ++n) acc[t][n] = (f32x4)(0.f);

    #pragma unroll
    for (int i = 0; i < 8; ++i) {
        int c = tid + i * 256;
        int r = c >> 4, c8 = c & 15;
        uint4 v = make_uint4(0u, 0u, 0u, 0u);
        int gr = row0 + r;
        if (gr < N_NODES) v = *(const uint4*)(A + (size_t)gr * DIM + c8 * 8);
        *(uint4*)(&As[r * 128 + (c8 ^ (r & 7)) * 8]) = v;
    }
    auto stageW = [&](const ushort_t* src) {
        #pragma unroll
        for (int i = 0; i < 8; ++i) {
            int c = tid + i * 256;
            int r = c >> 4, c8 = c & 15;
            uint4 v = *(const uint4*)(src + r * DIM + c8 * 8);
            *(uint4*)(&Ws[r * 128 + (c8 ^ (r & 7)) * 8]) = v;
        }
    };
    auto compute = [&]() {
        #pragma unroll
        for (int ks = 0; ks < 4; ++ks) {
            int m0 = wave * 32 + mn;
            int m1 = m0 + 16;
            frag8 a0 = *(const frag8*)&As[m0 * 128 + (((ks * 4 + q) ^ (m0 & 7)) * 8)];
            frag8 a1 = *(const frag8*)&As[m1 * 128 + (((ks * 4 + q) ^ (m1 & 7)) * 8)];
            #pragma unroll
            for (int n = 0; n < 8; ++n) {
                int nr = n * 16 + mn;
                frag8 b = *(const frag8*)&Ws[nr * 128 + (((ks * 4 + q) ^ (nr & 7)) * 8)];
                acc[0][n] = __builtin_amdgcn_mfma_f32_16x16x32_bf16(a0, b, acc[0][n], 0, 0, 0);
                acc[1][n] = __builtin_amdgcn_mfma_f32_16x16x32_bf16(a1, b, acc[1][n], 0, 0, 0);
            }
        }
    };

    // ---- GEMM 1: Z1 = relu(A@W1 + b1) ----
    stageW(W1h);
    __syncthreads(); compute(); __syncthreads();
    stageW(W1l);
    __syncthreads(); compute(); __syncthreads();

    // epilogue 1: write bf16 Z1 back into As (swizzled), reset acc
    int mloc = wave * 32;
    #pragma unroll
    for (int t = 0; t < 2; ++t) {
        #pragma unroll
        for (int n = 0; n < 8; ++n) {
            int col = n * 16 + mn;
            float bv = b1[col];
            #pragma unroll
            for (int r = 0; r < 4; ++r) {
                int rloc = mloc + t * 16 + q * 4 + r;
                float v = fmaxf(acc[t][n][r] + bv, 0.f);
                As[rloc * 128 + ((col >> 3) ^ (rloc & 7)) * 8 + (col & 7)] = bf16rne(v);
                acc[t][n][r] = 0.f;
            }
        }
    }
    __syncthreads();
    // ---- GEMM 2: Z = relu(Z1@W2 + b2) ----
    stageW(W2h);
    __syncthreads(); compute(); __syncthreads();
    stageW(W2l);
    __syncthreads(); compute();

    // epilogue 2: bf16 streaming store
    #pragma unroll
    for (int t = 0; t < 2; ++t) {
        #pragma unroll
        for (int n = 0; n < 8; ++n) {
            int col = n * 16 + mn;
            float bv = b2[col];
            #pragma unroll
            for (int r = 0; r < 4; ++r) {
                int grow = row0 + mloc + t * 16 + q * 4 + r;
                if (grow < N_NODES)
                    Zb[(size_t)grow * DIM + col] = bf16rne(fmaxf(acc[t][n][r] + bv, 0.f));
            }
        }
    }
}

// ---------------- fused GraphNorm (non-last): stats + apply + relu, bf16 out ----------------
__global__ __launch_bounds__(1024) void gn_fused(const unsigned* __restrict__ Zb, const int* __restrict__ gstart,
                                                 const float* __restrict__ scale, const float* __restrict__ weight,
                                                 const float* __restrict__ bias,
                                                 unsigned* __restrict__ Hb) {
    __shared__ float2 sh1[1024], sh2[1024];
    __shared__ float sa[128], sb[128];
    int g = blockIdx.x;
    int dp = threadIdx.x & 63, rg = threadIdx.x >> 6;
    int s = gstart[g], e = gstart[g + 1];
    float2 s1 = make_float2(0.f, 0.f), s2 = make_float2(0.f, 0.f);
    for (int n = s + rg; n < e; n += 16) {
        unsigned zz = Zb[(size_t)n * 64 + dp];
        float z0 = bfbits2f(zz & 0xffffu), z1 = bfbits2f(zz >> 16);
        s1.x += z0; s1.y += z1;
        s2.x += z0 * z0; s2.y += z1 * z1;
    }
    sh1[threadIdx.x] = s1;
    sh2[threadIdx.x] = s2;
    __syncthreads();
    if (rg == 0) {
        #pragma unroll
        for (int k = 1; k < 16; ++k) {
            float2 t1 = sh1[dp + 64 * k], t2 = sh2[dp + 64 * k];
            s1.x += t1.x; s1.y += t1.y;
            s2.x += t2.x; s2.y += t2.y;
        }
        int cnt = e - s;
        float cf = (float)(cnt > 0 ? cnt : 1);
        int d0 = dp * 2, d1 = d0 + 1;
        float m0 = s1.x / cf, m1 = s1.y / cf;
        float ez0 = s2.x / cf, ez1 = s2.y / cf;
        float sc0 = scale[d0], sc1 = scale[d1];
        float var0 = fmaxf(ez0 - (2.0f - sc0) * sc0 * m0 * m0, 0.f);
        float var1 = fmaxf(ez1 - (2.0f - sc1) * sc1 * m1 * m1, 0.f);
        sa[d0] = m0 * sc0;
        sa[d1] = m1 * sc1;
        sb[d0] = weight[d0] / sqrtf(var0 + GN_EPS);
        sb[d1] = weight[d1] / sqrtf(var1 + GN_EPS);
    }
    __syncthreads();
    int d0 = dp * 2, d1 = d0 + 1;
    float as0 = sa[d0], bm0 = sb[d0], bi0 = bias[d0];
    float as1 = sa[d1], bm1 = sb[d1], bi1 = bias[d1];
    for (int n = s + rg; n < e; n += 16) {
        unsigned zz = Zb[(size_t)n * 64 + dp];
        float z0 = bfbits2f(zz & 0xffffu), z1 = bfbits2f(zz >> 16);
        float o0 = fmaxf((z0 - as0) * bm0 + bi0, 0.f);
        float o1 = fmaxf((z1 - as1) * bm1 + bi1, 0.f);
        Hb[(size_t)n * 64 + dp] = packbf2(o0, o1);
    }
}

// ---------------- last layer: GraphNorm + relu + readout + final MLP + log_softmax, 1 block/graph ----
__global__ __launch_bounds__(1024) void gn_last(const unsigned* __restrict__ Zb, const int* __restrict__ gstart,
                                                const float* __restrict__ scale, const float* __restrict__ weight,
                                                const float* __restrict__ bias,
                                                const float* __restrict__ fw1, const float* __restrict__ fb1,
                                                const float* __restrict__ fw2, const float* __restrict__ fb2,
                                                const float* __restrict__ fw3, const float* __restrict__ fb3,
                                                float* __restrict__ out) {
    __shared__ float2 sh1[1024], sh2[1024];
    __shared__ float sa[128], sb[128];
    __shared__ float v0[128], v1[128], v2[128], lg[10];
    int g = blockIdx.x;
    int t = threadIdx.x;
    int dp = t & 63, rg = t >> 6;
    int s = gstart[g], e = gstart[g + 1];
    float2 s1 = make_float2(0.f, 0.f), s2 = make_float2(0.f, 0.f);
    for (int n = s + rg; n < e; n += 16) {
        unsigned zz = Zb[(size_t)n * 64 + dp];
        float z0 = bfbits2f(zz & 0xffffu), z1 = bfbits2f(zz >> 16);
        s1.x += z0; s1.y += z1;
        s2.x += z0 * z0; s2.y += z1 * z1;
    }
    sh1[t] = s1;
    sh2[t] = s2;
    __syncthreads();
    if (rg == 0) {
        #pragma unroll
        for (int k = 1; k < 16; ++k) {
            float2 t1 = sh1[dp + 64 * k], t2 = sh2[dp + 64 * k];
            s1.x += t1.x; s1.y += t1.y;
            s2.x += t2.x; s2.y += t2.y;
        }
        int cnt = e - s;
        float cf = (float)(cnt > 0 ? cnt : 1);
        int d0 = dp * 2, d1 = d0 + 1;
        float m0 = s1.x / cf, m1 = s1.y / cf;
        float ez0 = s2.x / cf, ez1 = s2.y / cf;
        float sc0 = scale[d0], sc1 = scale[d1];
        float var0 = fmaxf(ez0 - (2.0f - sc0) * sc0 * m0 * m0, 0.f);
        float var1 = fmaxf(ez1 - (2.0f - sc1) * sc1 * m1 * m1, 0.f);
        sa[d0] = m0 * sc0;
        sa[d1] = m1 * sc1;
        sb[d0] = weight[d0] / sqrtf(var0 + GN_EPS);
        sb[d1] = weight[d1] / sqrtf(var1 + GN_EPS);
    }
    __syncthreads();
    int d0 = dp * 2, d1 = d0 + 1;
    float as0 = sa[d0], bm0 = sb[d0], bi0 = bias[d0];
    float as1 = sa[d1], bm1 = sb[d1], bi1 = bias[d1];
    float2 rsum = make_float2(0.f, 0.f);
    for (int n = s + rg; n < e; n += 16) {
        unsigned zz = Zb[(size_t)n * 64 + dp];
        float z0 = bfbits2f(zz & 0xffffu), z1 = bfbits2f(zz >> 16);
        rsum.x += fmaxf((z0 - as0) * bm0 + bi0, 0.f);
        rsum.y += fmaxf((z1 - as1) * bm1 + bi1, 0.f);
    }
    __syncthreads();
    sh1[t] = rsum;
    __syncthreads();
    if (rg == 0) {
        #pragma unroll
        for (int k = 1; k < 16; ++k) {
            float2 t1 = sh1[dp + 64 * k];
            rsum.x += t1.x; rsum.y += t1.y;
        }
        v0[d0] = rsum.x;
        v0[d1] = rsum.y;
    }
    __syncthreads();
    // final MLP on first 128 threads
    if (t < 128) {
        float acc = fb1[t];
        for (int d = 0; d < 128; ++d) acc += v0[d] * fw1[d * 128 + t];
        v1[t] = fmaxf(acc, 0.f);
    }
    __syncthreads();
    if (t < 128) {
        float acc = fb2[t];
        for (int d = 0; d < 128; ++d) acc += v1[d] * fw2[d * 128 + t];
        v2[t] = fmaxf(acc, 0.f);
    }
    __syncthreads();
    if (t < 10) {
        float acc = fb3[t];
        for (int d = 0; d < 128; ++d) acc += v2[d] * fw3[d * 10 + t];
        lg[t] = acc;
    }
    __syncthreads();
    if (t < 10) {
        float m = -1e30f;
        for (int c = 0; c < 10; ++c) m = fmaxf(m, lg[c]);
        float ssum = 0.f;
        for (int c = 0; c < 10; ++c) ssum += expf(lg[c] - m);
        out[g * 10 + t] = lg[t] - m - logf(ssum);
    }
}

extern "C" void kernel_launch(void* const* d_in, const int* in_sizes, int n_in,
                              void* d_out, int out_size, void* d_ws, size_t ws_size,
                              hipStream_t stream) {
    const float* x      = (const float*)d_in[0];
    const float* gin_w1 = (const float*)d_in[1];
    const float* gin_b1 = (const float*)d_in[2];
    const float* gin_w2 = (const float*)d_in[3];
    const float* gin_b2 = (const float*)d_in[4];
    const float* gn_w   = (const float*)d_in[5];
    const float* gn_b   = (const float*)d_in[6];
    const float* gn_s   = (const float*)d_in[7];
    const float* fw1    = (const float*)d_in[8];
    const float* fb1    = (const float*)d_in[9];
    const float* fw2    = (const float*)d_in[10];
    const float* fb2    = (const float*)d_in[11];
    const float* fw3    = (const float*)d_in[12];
    const float* fb3    = (const float*)d_in[13];
    const int*   eidx   = (const int*)d_in[14];
    const int*   batch  = (const int*)d_in[15];
    float* out = (float*)d_out;

    const int* esrc = eidx;
    const int* edst = eidx + N_EDGES;

    auto align_up = [](size_t v) { return (v + 255) & ~(size_t)255; };
    char* p = (char*)d_ws;
    unsigned* Hb = (unsigned*)p;   p += align_up((size_t)N_NODES * DIM * 2);
    unsigned* Tb = (unsigned*)p;   p += align_up((size_t)N_NODES * DIM * 2);
    unsigned* Zb = (unsigned*)p;   p += align_up((size_t)N_NODES * DIM * 2);
    ushort_t* WThi = (ushort_t*)p; p += align_up((size_t)8 * DIM * DIM * 2);
    ushort_t* WTlo = (ushort_t*)p; p += align_up((size_t)8 * DIM * DIM * 2);
    int* gstart = (int*)p;         p += align_up((N_GRAPHS + 1) * 4);
    int* cnts = (int*)p;           p += align_up((size_t)NB * B_CHUNK * 4);
    int* off = (int*)p;            p += align_up(((size_t)NB * B_CHUNK + 1) * 4);
    int* bsum = (int*)p;           p += align_up(64 * 4);
    unsigned* ebuf = (unsigned*)p; p += align_up((size_t)N_EDGES * 4);
    int* eoff = (int*)p;           p += align_up((N_NODES + 1) * 4);
    int* csr = (int*)p;            p += align_up((size_t)N_EDGES * 4);

    const int SCAN_N = NB * B_CHUNK;                      // 25088
    const int SCAN_BLKS = (SCAN_N + 1023) / 1024;         // 25
    setup_misc<<<SETUP_BLKS, 256, 0, stream>>>(x, Hb, gin_w1, gin_w2, WThi, WTlo,
                                               batch, gstart, edst, cnts);
    scan_local<<<SCAN_BLKS, 1024, 0, stream>>>(cnts, off, bsum, SCAN_N);
    scan_block<<<1, 64, 0, stream>>>(bsum, SCAN_BLKS);
    scan_add<<<SCAN_BLKS, 1024, 0, stream>>>(off, bsum, SCAN_N, N_EDGES);
    p3_place<<<B_CHUNK, 256, 0, stream>>>(esrc, edst, off, ebuf);
    p4_csr<<<NB, 512, 0, stream>>>(ebuf, off, eoff, csr);

    const int mm_grid = (N_NODES + 127) / 128;
    for (int l = 0; l < N_LAYERS; ++l) {
        agg_bf16<<<(N_NODES + 3) / 4, 256, 0, stream>>>((const uint2*)Hb, eoff, csr, (uint2*)Tb);
        mm_layer<<<mm_grid, 256, 0, stream>>>((const ushort_t*)Tb,
            WThi + (size_t)(2 * l) * DIM * DIM, WTlo + (size_t)(2 * l) * DIM * DIM,
            WThi + (size_t)(2 * l + 1) * DIM * DIM, WTlo + (size_t)(2 * l + 1) * DIM * DIM,
            gin_b1 + l * DIM, gin_b2 + l * DIM, (ushort_t*)Zb);
        if (l == N_LAYERS - 1)
            gn_last<<<N_GRAPHS, 1024, 0, stream>>>(Zb, gstart, gn_s + l * DIM,
                gn_w + l * DIM, gn_b + l * DIM, fw1, fb1, fw2, fb2, fw3, fb3, out);
        else
            gn_fused<<<N_GRAPHS, 1024, 0, stream>>>(Zb, gstart, gn_s + l * DIM,
                gn_w + l * DIM, gn_b + l * DIM, Hb);
    }
}

// Round 9
// 412.009 us; speedup vs baseline: 2.6823x; 1.0385x over previous
//
#include <hip/hip_runtime.h>
#include <cstddef>

#define N_NODES 50000
#define N_EDGES 800000
#define N_GRAPHS 128
#define DIM 128
#define N_LAYERS 4
#define GN_EPS 1e-5f

// bucket-sort params
#define B_CHUNK 256        // chunk blocks
#define EPB 3125           // edges per chunk (256*3125 = 800000 exactly)
#define BUCKET_SHIFT 9
#define BUCKET_SIZE 512
#define NB 98              // ceil(50000/512)

// setup_misc grid partition
#define CX_BLKS 12500      // convert_x: 50000*64 uints / 256
#define CW_BLKS 512        // convert_w: 8*128*128 / 256
#define GB_BLKS 196        // graph_bounds: ceil(50000/256)
#define SETUP_BLKS (CX_BLKS + CW_BLKS + GB_BLKS + B_CHUNK)

typedef unsigned short ushort_t;
typedef __attribute__((ext_vector_type(8))) short frag8;
typedef __attribute__((ext_vector_type(4))) float f32x4;

__device__ inline float bfbits2f(unsigned hi16) { return __uint_as_float(hi16 << 16); }
__device__ inline ushort_t bf16rne(float v) {
    unsigned u = __float_as_uint(v);
    unsigned r = u + 0x7fff + ((u >> 16) & 1);
    return (ushort_t)(r >> 16);
}
__device__ inline unsigned packbf2(float a, float b) {
    return (unsigned)bf16rne(a) | ((unsigned)bf16rne(b) << 16);
}
__device__ inline void bf16split(float v, ushort_t& h, ushort_t& l) {
    ushort_t hi = bf16rne(v);
    float fh = __uint_as_float(((unsigned)hi) << 16);
    l = bf16rne(v - fh);
    h = hi;
}

// ---------------- merged independent setup: convert_x | convert_w | graph_bounds | p1_count ----
__global__ __launch_bounds__(256) void setup_misc(const float* __restrict__ x, unsigned* __restrict__ Hb,
                                                  const float* __restrict__ w1, const float* __restrict__ w2,
                                                  ushort_t* __restrict__ whi, ushort_t* __restrict__ wlo,
                                                  const int* __restrict__ batch, int* __restrict__ gstart,
                                                  const int* __restrict__ edst, int* __restrict__ cnts) {
    __shared__ int cnt[NB];
    int b = blockIdx.x, t = threadIdx.x;
    if (b < CX_BLKS) {
        int i = b * 256 + t;
        if (i < N_NODES * 64) {
            float a = x[2 * i], bb = x[2 * i + 1];
            Hb[i] = packbf2(a, bb);
        }
    } else if (b < CX_BLKS + CW_BLKS) {
        int idx = (b - CX_BLKS) * 256 + t;
        int mat = idx >> 14;
        int e = idx & 16383;
        int n = e >> 7, k = e & 127;
        int l = mat >> 1;
        const float* src = (mat & 1) ? (w2 + (size_t)l * DIM * DIM) : (w1 + (size_t)l * DIM * DIM);
        float v = src[k * DIM + n];
        ushort_t h, lw;
        bf16split(v, h, lw);
        whi[(size_t)mat * DIM * DIM + n * DIM + k] = h;
        wlo[(size_t)mat * DIM * DIM + n * DIM + k] = lw;
    } else if (b < CX_BLKS + CW_BLKS + GB_BLKS) {
        int i = (b - CX_BLKS - CW_BLKS) * 256 + t;
        if (i < N_NODES) {
            int bb = batch[i];
            if (i == 0) {
                for (int g = 0; g <= bb; ++g) gstart[g] = 0;
            } else {
                int pb = batch[i - 1];
                for (int g = pb + 1; g <= bb; ++g) gstart[g] = i;
            }
            if (i == N_NODES - 1) {
                for (int g = bb + 1; g <= N_GRAPHS; ++g) gstart[g] = N_NODES;
            }
        }
    } else {
        int blk = b - (CX_BLKS + CW_BLKS + GB_BLKS);
        for (int i = t; i < NB; i += 256) cnt[i] = 0;
        __syncthreads();
        int base = blk * EPB;
        for (int i = t; i < EPB; i += 256) atomicAdd(&cnt[edst[base + i] >> BUCKET_SHIFT], 1);
        __syncthreads();
        for (int i = t; i < NB; i += 256) cnts[i * B_CHUNK + blk] = cnt[i];
    }
}

// ---------------- 3-phase scan (over NB*B_CHUNK = 25088) ----------------
__global__ __launch_bounds__(1024) void scan_local(const int* __restrict__ in, int* __restrict__ out,
                                                   int* __restrict__ bsum, int n) {
    __shared__ int wsum[16];
    int tid = threadIdx.x, lane = tid & 63, w = tid >> 6;
    int gi = blockIdx.x * 1024 + tid;
    int v = (gi < n) ? in[gi] : 0;
    int s = v;
    #pragma unroll
    for (int off = 1; off < 64; off <<= 1) {
        int t = __shfl_up(s, off, 64);
        if (lane >= off) s += t;
    }
    if (lane == 63) wsum[w] = s;
    __syncthreads();
    if (w == 0) {
        int ws = (lane < 16) ? wsum[lane] : 0;
        #pragma unroll
        for (int off = 1; off < 16; off <<= 1) {
            int t = __shfl_up(ws, off, 64);
            if (lane >= off) ws += t;
        }
        if (lane < 16) wsum[lane] = ws;
    }
    __syncthreads();
    int woff = (w > 0) ? wsum[w - 1] : 0;
    if (gi < n) out[gi] = woff + s - v;
    if (tid == 1023) bsum[blockIdx.x] = woff + s;
}

__global__ __launch_bounds__(64) void scan_block(int* __restrict__ bsum, int nb) {
    int lane = threadIdx.x;
    int v = (lane < nb) ? bsum[lane] : 0;
    int s = v;
    #pragma unroll
    for (int off = 1; off < 64; off <<= 1) {
        int t = __shfl_up(s, off, 64);
        if (lane >= off) s += t;
    }
    if (lane < nb) bsum[lane] = s - v;
}

__global__ __launch_bounds__(1024) void scan_add(int* __restrict__ out, const int* __restrict__ bsum, int n, int total) {
    int gi = blockIdx.x * 1024 + threadIdx.x;
    if (gi < n) out[gi] += bsum[blockIdx.x];
    if (blockIdx.x == 0 && threadIdx.x == 0) out[n] = total;
}

// ---------------- bucket CSR phase 3: place packed (dstfine<<16 | src) into bucket-major ebuf ----
__global__ __launch_bounds__(256) void p3_place(const int* __restrict__ src, const int* __restrict__ dst,
                                                const int* __restrict__ off, unsigned* __restrict__ ebuf) {
    __shared__ int cur[NB];
    int t = threadIdx.x, blk = blockIdx.x;
    for (int i = t; i < NB; i += 256) cur[i] = off[i * B_CHUNK + blk];
    __syncthreads();
    int base = blk * EPB;
    for (int i = t; i < EPB; i += 256) {
        int d = dst[base + i];
        int b = d >> BUCKET_SHIFT;
        int pos = atomicAdd(&cur[b], 1);
        ebuf[pos] = (unsigned)src[base + i] | ((unsigned)(d & (BUCKET_SIZE - 1)) << 16);
    }
}

// ---------------- bucket CSR phase 4: per-bucket counting sort -> eoff + csr ----------------
__global__ __launch_bounds__(512) void p4_csr(const unsigned* __restrict__ ebuf, const int* __restrict__ off,
                                              int* __restrict__ eoff, int* __restrict__ csr) {
    __shared__ int cnt[BUCKET_SIZE];
    __shared__ int wsum[8];
    int k = blockIdx.x, t = threadIdx.x;
    int bstart = off[k * B_CHUNK];
    int bend = off[(k + 1) * B_CHUNK];
    cnt[t] = 0;
    __syncthreads();
    for (int i = bstart + t; i < bend; i += 512) atomicAdd(&cnt[ebuf[i] >> 16], 1);
    __syncthreads();
    int lane = t & 63, w = t >> 6;
    int v = cnt[t], s = v;
    #pragma unroll
    for (int o = 1; o < 64; o <<= 1) {
        int tt = __shfl_up(s, o, 64);
        if (lane >= o) s += tt;
    }
    if (lane == 63) wsum[w] = s;
    __syncthreads();
    if (w == 0) {
        int ws = (lane < 8) ? wsum[lane] : 0;
        #pragma unroll
        for (int o = 1; o < 8; o <<= 1) {
            int tt = __shfl_up(ws, o, 64);
            if (lane >= o) ws += tt;
        }
        if (lane < 8) wsum[lane] = ws;
    }
    __syncthreads();
    int woff = (w > 0) ? wsum[w - 1] : 0;
    int excl = woff + s - v;
    int node = k * BUCKET_SIZE + t;
    if (node < N_NODES) eoff[node] = bstart + excl;
    __syncthreads();
    cnt[t] = excl;  // reuse as cursor
    __syncthreads();
    for (int i = bstart + t; i < bend; i += 512) {
        unsigned p = ebuf[i];
        int pos = atomicAdd(&cnt[p >> 16], 1);
        csr[bstart + pos] = (int)(p & 0xffffu);
    }
    if (k == NB - 1 && t == 0) eoff[N_NODES] = N_EDGES;
}

// ---------------- GIN aggregation v4: quarter-wave edge parallelism, uint4 lanes ----------------
// one wave per node; 4 quarters (16 lanes x uint4 = 256 B row each) process edges 4i+qtr
// concurrently -> 16 gathers in flight in the unrolled loop. Trip counts are WAVE-UNIFORM;
// every __shfl is executed by all 64 lanes (predicate only guards accumulation).
__global__ __launch_bounds__(256) void agg_bf16(const uint4* __restrict__ h4, const int* __restrict__ eoff,
                                                const int* __restrict__ csr, uint4* __restrict__ T4) {
    int wid = (blockIdx.x * 256 + threadIdx.x) >> 6;
    int lane = threadIdx.x & 63;
    int qtr = lane >> 4;
    int ql = lane & 15;
    if (wid >= N_NODES) return;
    int lo = eoff[wid], hi = eoff[wid + 1];

    float a[8];
    #pragma unroll
    for (int k = 0; k < 8; ++k) a[k] = 0.f;

    auto acc_row = [&](uint4 w) {
        a[0] += bfbits2f(w.x & 0xffffu); a[1] += bfbits2f(w.x >> 16);
        a[2] += bfbits2f(w.y & 0xffffu); a[3] += bfbits2f(w.y >> 16);
        a[4] += bfbits2f(w.z & 0xffffu); a[5] += bfbits2f(w.z >> 16);
        a[6] += bfbits2f(w.w & 0xffffu); a[7] += bfbits2f(w.w >> 16);
    };

    if (qtr == 0) acc_row(h4[(size_t)wid * 16 + ql]);  // self term

    for (int base = lo; base < hi; base += 64) {
        int nav = hi - base;
        if (nav > 64) nav = 64;
        int jv = (base + lane < hi) ? csr[base + lane] : 0;  // one coalesced index load
        int cmin = nav >> 2;         // iterations where ALL four quarters have a valid edge
        int cmax = (nav + 3) >> 2;   // uniform loop bound for the whole wave
        int i = 0;
        for (; i + 3 < cmin; i += 4) {  // 16 edges in flight across the wave
            int j0 = __shfl(jv, 4 * (i + 0) + qtr, 64);
            int j1 = __shfl(jv, 4 * (i + 1) + qtr, 64);
            int j2 = __shfl(jv, 4 * (i + 2) + qtr, 64);
            int j3 = __shfl(jv, 4 * (i + 3) + qtr, 64);
            uint4 w0 = h4[(size_t)j0 * 16 + ql];
            uint4 w1 = h4[(size_t)j1 * 16 + ql];
            uint4 w2 = h4[(size_t)j2 * 16 + ql];
            uint4 w3 = h4[(size_t)j3 * 16 + ql];
            acc_row(w0); acc_row(w1); acc_row(w2); acc_row(w3);
        }
        for (; i < cmin; ++i) {          // leftover full quads (uniform bound)
            int j = __shfl(jv, 4 * i + qtr, 64);
            acc_row(h4[(size_t)j * 16 + ql]);
        }
        for (; i < cmax; ++i) {          // partial tail: shfl BEFORE the predicate
            int epos = 4 * i + qtr;      // <= 63 always (nav <= 64)
            int j = __shfl(jv, epos, 64);
            if (epos < nav) acc_row(h4[(size_t)j * 16 + ql]);
        }
    }

    // cross-quarter combine (all lanes active): q0+q2 / q1+q3 then +16
    #pragma unroll
    for (int k = 0; k < 8; ++k) {
        a[k] += __shfl_down(a[k], 32, 64);
        a[k] += __shfl_down(a[k], 16, 64);
    }
    if (qtr == 0) {
        uint4 o;
        o.x = packbf2(a[0], a[1]);
        o.y = packbf2(a[2], a[3]);
        o.z = packbf2(a[4], a[5]);
        o.w = packbf2(a[6], a[7]);
        T4[(size_t)wid * 16 + ql] = o;
    }
}

// ---------------- fused layer GEMM: Zb = relu(relu(T@W1+b1)@W2+b2), bf16 out ----------
// 128x128 per block, 4 waves, XOR-swizzled LDS; Z1 round-trips through As in LDS.
__global__ __launch_bounds__(256) void mm_layer(const ushort_t* __restrict__ A,
                                                const ushort_t* __restrict__ W1h, const ushort_t* __restrict__ W1l,
                                                const ushort_t* __restrict__ W2h, const ushort_t* __restrict__ W2l,
                                                const float* __restrict__ b1, const float* __restrict__ b2,
                                                ushort_t* __restrict__ Zb) {
    __shared__ ushort_t As[128 * 128];
    __shared__ ushort_t Ws[128 * 128];
    int tid = threadIdx.x;
    int row0 = blockIdx.x * 128;
    int wave = tid >> 6, lane = tid & 63;
    int q = lane >> 4, mn = lane & 15;

    f32x4 acc[2][8];
    #pragma unroll
    for (int t = 0; t < 2; ++t)
        #pragma unroll
        for (int n = 0; n < 8; ++n) acc[t][n] = (f32x4)(0.f);

    #pragma unroll
    for (int i = 0; i < 8; ++i) {
        int c = tid + i * 256;
        int r = c >> 4, c8 = c & 15;
        uint4 v = make_uint4(0u, 0u, 0u, 0u);
        int gr = row0 + r;
        if (gr < N_NODES) v = *(const uint4*)(A + (size_t)gr * DIM + c8 * 8);
        *(uint4*)(&As[r * 128 + (c8 ^ (r & 7)) * 8]) = v;
    }
    auto stageW = [&](const ushort_t* src) {
        #pragma unroll
        for (int i = 0; i < 8; ++i) {
            int c = tid + i * 256;
            int r = c >> 4, c8 = c & 15;
            uint4 v = *(const uint4*)(src + r * DIM + c8 * 8);
            *(uint4*)(&Ws[r * 128 + (c8 ^ (r & 7)) * 8]) = v;
        }
    };
    auto compute = [&]() {
        #pragma unroll
        for (int ks = 0; ks < 4; ++ks) {
            int m0 = wave * 32 + mn;
            int m1 = m0 + 16;
            frag8 a0 = *(const frag8*)&As[m0 * 128 + (((ks * 4 + q) ^ (m0 & 7)) * 8)];
            frag8 a1 = *(const frag8*)&As[m1 * 128 + (((ks * 4 + q) ^ (m1 & 7)) * 8)];
            #pragma unroll
            for (int n = 0; n < 8; ++n) {
                int nr = n * 16 + mn;
                frag8 b = *(const frag8*)&Ws[nr * 128 + (((ks * 4 + q) ^ (nr & 7)) * 8)];
                acc[0][n] = __builtin_amdgcn_mfma_f32_16x16x32_bf16(a0, b, acc[0][n], 0, 0, 0);
                acc[1][n] = __builtin_amdgcn_mfma_f32_16x16x32_bf16(a1, b, acc[1][n], 0, 0, 0);
            }
        }
    };

    // ---- GEMM 1: Z1 = relu(A@W1 + b1) ----
    stageW(W1h);
    __syncthreads(); compute(); __syncthreads();
    stageW(W1l);
    __syncthreads(); compute(); __syncthreads();

    // epilogue 1: write bf16 Z1 back into As (swizzled), reset acc
    int mloc = wave * 32;
    #pragma unroll
    for (int t = 0; t < 2; ++t) {
        #pragma unroll
        for (int n = 0; n < 8; ++n) {
            int col = n * 16 + mn;
            float bv = b1[col];
            #pragma unroll
            for (int r = 0; r < 4; ++r) {
                int rloc = mloc + t * 16 + q * 4 + r;
                float v = fmaxf(acc[t][n][r] + bv, 0.f);
                As[rloc * 128 + ((col >> 3) ^ (rloc & 7)) * 8 + (col & 7)] = bf16rne(v);
                acc[t][n][r] = 0.f;
            }
        }
    }
    __syncthreads();
    // ---- GEMM 2: Z = relu(Z1@W2 + b2) ----
    stageW(W2h);
    __syncthreads(); compute(); __syncthreads();
    stageW(W2l);
    __syncthreads(); compute();

    // epilogue 2: bf16 streaming store
    #pragma unroll
    for (int t = 0; t < 2; ++t) {
        #pragma unroll
        for (int n = 0; n < 8; ++n) {
            int col = n * 16 + mn;
            float bv = b2[col];
            #pragma unroll
            for (int r = 0; r < 4; ++r) {
                int grow = row0 + mloc + t * 16 + q * 4 + r;
                if (grow < N_NODES)
                    Zb[(size_t)grow * DIM + col] = bf16rne(fmaxf(acc[t][n][r] + bv, 0.f));
            }
        }
    }
}

// ---------------- fused GraphNorm (non-last), DIM-SPLIT: 2 blocks per graph ----------------
// block = g*2+half handles dims [half*64, half*64+64); GraphNorm is per-dim so halves are
// independent. 1024 threads = 32 row-groups x 32 dim-uints; 128 B coalesced row segments.
__global__ __launch_bounds__(1024) void gn_fused(const unsigned* __restrict__ Zb, const int* __restrict__ gstart,
                                                 const float* __restrict__ scale, const float* __restrict__ weight,
                                                 const float* __restrict__ bias,
                                                 unsigned* __restrict__ Hb) {
    __shared__ float2 sh1[1024], sh2[1024];
    __shared__ float sa[64], sb[64];
    int g = blockIdx.x >> 1, half = blockIdx.x & 1;
    int dpl = threadIdx.x & 31, rg = threadIdx.x >> 5;
    int dp = half * 32 + dpl;               // uint column in [0,64)
    int s = gstart[g], e = gstart[g + 1];
    float2 s1 = make_float2(0.f, 0.f), s2 = make_float2(0.f, 0.f);
    for (int n = s + rg; n < e; n += 32) {
        unsigned zz = Zb[(size_t)n * 64 + dp];
        float z0 = bfbits2f(zz & 0xffffu), z1 = bfbits2f(zz >> 16);
        s1.x += z0; s1.y += z1;
        s2.x += z0 * z0; s2.y += z1 * z1;
    }
    sh1[threadIdx.x] = s1;
    sh2[threadIdx.x] = s2;
    __syncthreads();
    if (rg == 0) {
        #pragma unroll
        for (int k = 1; k < 32; ++k) {
            float2 t1 = sh1[dpl + 32 * k], t2 = sh2[dpl + 32 * k];
            s1.x += t1.x; s1.y += t1.y;
            s2.x += t2.x; s2.y += t2.y;
        }
        int cnt = e - s;
        float cf = (float)(cnt > 0 ? cnt : 1);
        int d0 = dp * 2, d1 = d0 + 1;
        float m0 = s1.x / cf, m1 = s1.y / cf;
        float ez0 = s2.x / cf, ez1 = s2.y / cf;
        float sc0 = scale[d0], sc1 = scale[d1];
        float var0 = fmaxf(ez0 - (2.0f - sc0) * sc0 * m0 * m0, 0.f);
        float var1 = fmaxf(ez1 - (2.0f - sc1) * sc1 * m1 * m1, 0.f);
        sa[dpl * 2] = m0 * sc0;
        sa[dpl * 2 + 1] = m1 * sc1;
        sb[dpl * 2] = weight[d0] / sqrtf(var0 + GN_EPS);
        sb[dpl * 2 + 1] = weight[d1] / sqrtf(var1 + GN_EPS);
    }
    __syncthreads();
    float as0 = sa[dpl * 2], bm0 = sb[dpl * 2], bi0 = bias[dp * 2];
    float as1 = sa[dpl * 2 + 1], bm1 = sb[dpl * 2 + 1], bi1 = bias[dp * 2 + 1];
    for (int n = s + rg; n < e; n += 32) {
        unsigned zz = Zb[(size_t)n * 64 + dp];
        float z0 = bfbits2f(zz & 0xffffu), z1 = bfbits2f(zz >> 16);
        float o0 = fmaxf((z0 - as0) * bm0 + bi0, 0.f);
        float o1 = fmaxf((z1 - as1) * bm1 + bi1, 0.f);
        Hb[(size_t)n * 64 + dp] = packbf2(o0, o1);
    }
}

// ---------------- last layer: GraphNorm + relu + readout + final MLP + log_softmax, 1 block/graph ----
__global__ __launch_bounds__(1024) void gn_last(const unsigned* __restrict__ Zb, const int* __restrict__ gstart,
                                                const float* __restrict__ scale, const float* __restrict__ weight,
                                                const float* __restrict__ bias,
                                                const float* __restrict__ fw1, const float* __restrict__ fb1,
                                                const float* __restrict__ fw2, const float* __restrict__ fb2,
                                                const float* __restrict__ fw3, const float* __restrict__ fb3,
                                                float* __restrict__ out) {
    __shared__ float2 sh1[1024], sh2[1024];
    __shared__ float sa[128], sb[128];
    __shared__ float v0[128], v1[128], v2[128], lg[10];
    int g = blockIdx.x;
    int t = threadIdx.x;
    int dp = t & 63, rg = t >> 6;
    int s = gstart[g], e = gstart[g + 1];
    float2 s1 = make_float2(0.f, 0.f), s2 = make_float2(0.f, 0.f);
    for (int n = s + rg; n < e; n += 16) {
        unsigned zz = Zb[(size_t)n * 64 + dp];
        float z0 = bfbits2f(zz & 0xffffu), z1 = bfbits2f(zz >> 16);
        s1.x += z0; s1.y += z1;
        s2.x += z0 * z0; s2.y += z1 * z1;
    }
    sh1[t] = s1;
    sh2[t] = s2;
    __syncthreads();
    if (rg == 0) {
        #pragma unroll
        for (int k = 1; k < 16; ++k) {
            float2 t1 = sh1[dp + 64 * k], t2 = sh2[dp + 64 * k];
            s1.x += t1.x; s1.y += t1.y;
            s2.x += t2.x; s2.y += t2.y;
        }
        int cnt = e - s;
        float cf = (float)(cnt > 0 ? cnt : 1);
        int d0 = dp * 2, d1 = d0 + 1;
        float m0 = s1.x / cf, m1 = s1.y / cf;
        float ez0 = s2.x / cf, ez1 = s2.y / cf;
        float sc0 = scale[d0], sc1 = scale[d1];
        float var0 = fmaxf(ez0 - (2.0f - sc0) * sc0 * m0 * m0, 0.f);
        float var1 = fmaxf(ez1 - (2.0f - sc1) * sc1 * m1 * m1, 0.f);
        sa[d0] = m0 * sc0;
        sa[d1] = m1 * sc1;
        sb[d0] = weight[d0] / sqrtf(var0 + GN_EPS);
        sb[d1] = weight[d1] / sqrtf(var1 + GN_EPS);
    }
    __syncthreads();
    int d0 = dp * 2, d1 = d0 + 1;
    float as0 = sa[d0], bm0 = sb[d0], bi0 = bias[d0];
    float as1 = sa[d1], bm1 = sb[d1], bi1 = bias[d1];
    float2 rsum = make_float2(0.f, 0.f);
    for (int n = s + rg; n < e; n += 16) {
        unsigned zz = Zb[(size_t)n * 64 + dp];
        float z0 = bfbits2f(zz & 0xffffu), z1 = bfbits2f(zz >> 16);
        rsum.x += fmaxf((z0 - as0) * bm0 + bi0, 0.f);
        rsum.y += fmaxf((z1 - as1) * bm1 + bi1, 0.f);
    }
    __syncthreads();
    sh1[t] = rsum;
    __syncthreads();
    if (rg == 0) {
        #pragma unroll
        for (int k = 1; k < 16; ++k) {
            float2 t1 = sh1[dp + 64 * k];
            rsum.x += t1.x; rsum.y += t1.y;
        }
        v0[d0] = rsum.x;
        v0[d1] = rsum.y;
    }
    __syncthreads();
    // final MLP on first 128 threads
    if (t < 128) {
        float acc = fb1[t];
        for (int d = 0; d < 128; ++d) acc += v0[d] * fw1[d * 128 + t];
        v1[t] = fmaxf(acc, 0.f);
    }
    __syncthreads();
    if (t < 128) {
        float acc = fb2[t];
        for (int d = 0; d < 128; ++d) acc += v1[d] * fw2[d * 128 + t];
        v2[t] = fmaxf(acc, 0.f);
    }
    __syncthreads();
    if (t < 10) {
        float acc = fb3[t];
        for (int d = 0; d < 128; ++d) acc += v2[d] * fw3[d * 10 + t];
        lg[t] = acc;
    }
    __syncthreads();
    if (t < 10) {
        float m = -1e30f;
        for (int c = 0; c < 10; ++c) m = fmaxf(m, lg[c]);
        float ssum = 0.f;
        for (int c = 0; c < 10; ++c) ssum += expf(lg[c] - m);
        out[g * 10 + t] = lg[t] - m - logf(ssum);
    }
}

extern "C" void kernel_launch(void* const* d_in, const int* in_sizes, int n_in,
                              void* d_out, int out_size, void* d_ws, size_t ws_size,
                              hipStream_t stream) {
    const float* x      = (const float*)d_in[0];
    const float* gin_w1 = (const float*)d_in[1];
    const float* gin_b1 = (const float*)d_in[2];
    const float* gin_w2 = (const float*)d_in[3];
    const float* gin_b2 = (const float*)d_in[4];
    const float* gn_w   = (const float*)d_in[5];
    const float* gn_b   = (const float*)d_in[6];
    const float* gn_s   = (const float*)d_in[7];
    const float* fw1    = (const float*)d_in[8];
    const float* fb1    = (const float*)d_in[9];
    const float* fw2    = (const float*)d_in[10];
    const float* fb2    = (const float*)d_in[11];
    const float* fw3    = (const float*)d_in[12];
    const float* fb3    = (const float*)d_in[13];
    const int*   eidx   = (const int*)d_in[14];
    const int*   batch  = (const int*)d_in[15];
    float* out = (float*)d_out;

    const int* esrc = eidx;
    const int* edst = eidx + N_EDGES;

    auto align_up = [](size_t v) { return (v + 255) & ~(size_t)255; };
    char* p = (char*)d_ws;
    unsigned* Hb = (unsigned*)p;   p += align_up((size_t)N_NODES * DIM * 2);
    unsigned* Tb = (unsigned*)p;   p += align_up((size_t)N_NODES * DIM * 2);
    unsigned* Zb = (unsigned*)p;   p += align_up((size_t)N_NODES * DIM * 2);
    ushort_t* WThi = (ushort_t*)p; p += align_up((size_t)8 * DIM * DIM * 2);
    ushort_t* WTlo = (ushort_t*)p; p += align_up((size_t)8 * DIM * DIM * 2);
    int* gstart = (int*)p;         p += align_up((N_GRAPHS + 1) * 4);
    int* cnts = (int*)p;           p += align_up((size_t)NB * B_CHUNK * 4);
    int* off = (int*)p;            p += align_up(((size_t)NB * B_CHUNK + 1) * 4);
    int* bsum = (int*)p;           p += align_up(64 * 4);
    unsigned* ebuf = (unsigned*)p; p += align_up((size_t)N_EDGES * 4);
    int* eoff = (int*)p;           p += align_up((N_NODES + 1) * 4);
    int* csr = (int*)p;            p += align_up((size_t)N_EDGES * 4);

    const int SCAN_N = NB * B_CHUNK;                      // 25088
    const int SCAN_BLKS = (SCAN_N + 1023) / 1024;         // 25
    setup_misc<<<SETUP_BLKS, 256, 0, stream>>>(x, Hb, gin_w1, gin_w2, WThi, WTlo,
                                               batch, gstart, edst, cnts);
    scan_local<<<SCAN_BLKS, 1024, 0, stream>>>(cnts, off, bsum, SCAN_N);
    scan_block<<<1, 64, 0, stream>>>(bsum, SCAN_BLKS);
    scan_add<<<SCAN_BLKS, 1024, 0, stream>>>(off, bsum, SCAN_N, N_EDGES);
    p3_place<<<B_CHUNK, 256, 0, stream>>>(esrc, edst, off, ebuf);
    p4_csr<<<NB, 512, 0, stream>>>(ebuf, off, eoff, csr);

    const int mm_grid = (N_NODES + 127) / 128;
    for (int l = 0; l < N_LAYERS; ++l) {
        agg_bf16<<<(N_NODES + 3) / 4, 256, 0, stream>>>((const uint4*)Hb, eoff, csr, (uint4*)Tb);
        mm_layer<<<mm_grid, 256, 0, stream>>>((const ushort_t*)Tb,
            WThi + (size_t)(2 * l) * DIM * DIM, WTlo + (size_t)(2 * l) * DIM * DIM,
            WThi + (size_t)(2 * l + 1) * DIM * DIM, WTlo + (size_t)(2 * l + 1) * DIM * DIM,
            gin_b1 + l * DIM, gin_b2 + l * DIM, (ushort_t*)Zb);
        if (l == N_LAYERS - 1)
            gn_last<<<N_GRAPHS, 1024, 0, stream>>>(Zb, gstart, gn_s + l * DIM,
                gn_w + l * DIM, gn_b + l * DIM, fw1, fb1, fw2, fb2, fw3, fb3, out);
        else
            gn_fused<<<N_GRAPHS * 2, 1024, 0, stream>>>(Zb, gstart, gn_s + l * DIM,
                gn_w + l * DIM, gn_b + l * DIM, Hb);
    }
}

// Round 10
// 382.846 us; speedup vs baseline: 2.8866x; 1.0762x over previous
//
#include <hip/hip_runtime.h>
#include <cstddef>

#define N_NODES 50000
#define N_EDGES 800000
#define N_GRAPHS 128
#define DIM 128
#define N_LAYERS 4
#define GN_EPS 1e-5f

// bucket-sort params
#define B_CHUNK 256        // chunk blocks
#define EPB 3125           // edges per chunk (256*3125 = 800000 exactly)
#define BUCKET_SHIFT 9
#define BUCKET_SIZE 512
#define NB 98              // ceil(50000/512)

// setup_misc grid partition
#define CX_BLKS 12500      // convert_x: 50000*64 uints / 256
#define CW_BLKS 512        // convert_w: 8*128*128 / 256
#define GB_BLKS 196        // graph_bounds: ceil(50000/256)
#define SETUP_BLKS (CX_BLKS + CW_BLKS + GB_BLKS + B_CHUNK)

typedef unsigned short ushort_t;
typedef __attribute__((ext_vector_type(8))) short frag8;
typedef __attribute__((ext_vector_type(4))) float f32x4;

__device__ inline float bfbits2f(unsigned hi16) { return __uint_as_float(hi16 << 16); }
__device__ inline ushort_t bf16rne(float v) {
    unsigned u = __float_as_uint(v);
    unsigned r = u + 0x7fff + ((u >> 16) & 1);
    return (ushort_t)(r >> 16);
}
__device__ inline unsigned packbf2(float a, float b) {
    return (unsigned)bf16rne(a) | ((unsigned)bf16rne(b) << 16);
}
__device__ inline void bf16split(float v, ushort_t& h, ushort_t& l) {
    ushort_t hi = bf16rne(v);
    float fh = __uint_as_float(((unsigned)hi) << 16);
    l = bf16rne(v - fh);
    h = hi;
}

// ---------------- merged independent setup: convert_x | convert_w | graph_bounds | p1_count ----
__global__ __launch_bounds__(256) void setup_misc(const float* __restrict__ x, unsigned* __restrict__ Hb,
                                                  const float* __restrict__ w1, const float* __restrict__ w2,
                                                  ushort_t* __restrict__ whi, ushort_t* __restrict__ wlo,
                                                  const int* __restrict__ batch, int* __restrict__ gstart,
                                                  const int* __restrict__ edst, int* __restrict__ cnts) {
    __shared__ int cnt[NB];
    int b = blockIdx.x, t = threadIdx.x;
    if (b < CX_BLKS) {
        int i = b * 256 + t;
        if (i < N_NODES * 64) {
            float a = x[2 * i], bb = x[2 * i + 1];
            Hb[i] = packbf2(a, bb);
        }
    } else if (b < CX_BLKS + CW_BLKS) {
        int idx = (b - CX_BLKS) * 256 + t;
        int mat = idx >> 14;
        int e = idx & 16383;
        int n = e >> 7, k = e & 127;
        int l = mat >> 1;
        const float* src = (mat & 1) ? (w2 + (size_t)l * DIM * DIM) : (w1 + (size_t)l * DIM * DIM);
        float v = src[k * DIM + n];
        ushort_t h, lw;
        bf16split(v, h, lw);
        whi[(size_t)mat * DIM * DIM + n * DIM + k] = h;
        wlo[(size_t)mat * DIM * DIM + n * DIM + k] = lw;
    } else if (b < CX_BLKS + CW_BLKS + GB_BLKS) {
        int i = (b - CX_BLKS - CW_BLKS) * 256 + t;
        if (i < N_NODES) {
            int bb = batch[i];
            if (i == 0) {
                for (int g = 0; g <= bb; ++g) gstart[g] = 0;
            } else {
                int pb = batch[i - 1];
                for (int g = pb + 1; g <= bb; ++g) gstart[g] = i;
            }
            if (i == N_NODES - 1) {
                for (int g = bb + 1; g <= N_GRAPHS; ++g) gstart[g] = N_NODES;
            }
        }
    } else {
        int blk = b - (CX_BLKS + CW_BLKS + GB_BLKS);
        for (int i = t; i < NB; i += 256) cnt[i] = 0;
        __syncthreads();
        int base = blk * EPB;
        for (int i = t; i < EPB; i += 256) atomicAdd(&cnt[edst[base + i] >> BUCKET_SHIFT], 1);
        __syncthreads();
        for (int i = t; i < NB; i += 256) cnts[i * B_CHUNK + blk] = cnt[i];
    }
}

// ---------------- scan phase 1 (over NB*B_CHUNK = 25088) ----------------
__global__ __launch_bounds__(1024) void scan_local(const int* __restrict__ in, int* __restrict__ out,
                                                   int* __restrict__ bsum, int n) {
    __shared__ int wsum[16];
    int tid = threadIdx.x, lane = tid & 63, w = tid >> 6;
    int gi = blockIdx.x * 1024 + tid;
    int v = (gi < n) ? in[gi] : 0;
    int s = v;
    #pragma unroll
    for (int off = 1; off < 64; off <<= 1) {
        int t = __shfl_up(s, off, 64);
        if (lane >= off) s += t;
    }
    if (lane == 63) wsum[w] = s;
    __syncthreads();
    if (w == 0) {
        int ws = (lane < 16) ? wsum[lane] : 0;
        #pragma unroll
        for (int off = 1; off < 16; off <<= 1) {
            int t = __shfl_up(ws, off, 64);
            if (lane >= off) ws += t;
        }
        if (lane < 16) wsum[lane] = ws;
    }
    __syncthreads();
    int woff = (w > 0) ? wsum[w - 1] : 0;
    if (gi < n) out[gi] = woff + s - v;
    if (tid == 1023) bsum[blockIdx.x] = woff + s;
}

// ---------------- scan phase 2: each wave redundantly reduces bsum[0..bid) via butterfly ----
__global__ __launch_bounds__(1024) void scan_add(int* __restrict__ out, const int* __restrict__ bsum,
                                                 int n, int total) {
    int lane = threadIdx.x & 63;
    int v = (lane < (int)blockIdx.x) ? bsum[lane] : 0;  // SCAN_BLKS <= 64
    #pragma unroll
    for (int off = 1; off < 64; off <<= 1) v += __shfl_xor(v, off, 64);
    int gi = blockIdx.x * 1024 + threadIdx.x;
    if (gi < n) out[gi] += v;
    if (blockIdx.x == 0 && threadIdx.x == 0) out[n] = total;
}

// ---------------- bucket CSR phase 3: place packed (dstfine<<16 | src) into bucket-major ebuf ----
__global__ __launch_bounds__(256) void p3_place(const int* __restrict__ src, const int* __restrict__ dst,
                                                const int* __restrict__ off, unsigned* __restrict__ ebuf) {
    __shared__ int cur[NB];
    int t = threadIdx.x, blk = blockIdx.x;
    for (int i = t; i < NB; i += 256) cur[i] = off[i * B_CHUNK + blk];
    __syncthreads();
    int base = blk * EPB;
    for (int i = t; i < EPB; i += 256) {
        int d = dst[base + i];
        int b = d >> BUCKET_SHIFT;
        int pos = atomicAdd(&cur[b], 1);
        ebuf[pos] = (unsigned)src[base + i] | ((unsigned)(d & (BUCKET_SIZE - 1)) << 16);
    }
}

// ---------------- bucket CSR phase 4: per-bucket counting sort -> eoff + csr ----------------
__global__ __launch_bounds__(512) void p4_csr(const unsigned* __restrict__ ebuf, const int* __restrict__ off,
                                              int* __restrict__ eoff, int* __restrict__ csr) {
    __shared__ int cnt[BUCKET_SIZE];
    __shared__ int wsum[8];
    int k = blockIdx.x, t = threadIdx.x;
    int bstart = off[k * B_CHUNK];
    int bend = off[(k + 1) * B_CHUNK];
    cnt[t] = 0;
    __syncthreads();
    for (int i = bstart + t; i < bend; i += 512) atomicAdd(&cnt[ebuf[i] >> 16], 1);
    __syncthreads();
    int lane = t & 63, w = t >> 6;
    int v = cnt[t], s = v;
    #pragma unroll
    for (int o = 1; o < 64; o <<= 1) {
        int tt = __shfl_up(s, o, 64);
        if (lane >= o) s += tt;
    }
    if (lane == 63) wsum[w] = s;
    __syncthreads();
    if (w == 0) {
        int ws = (lane < 8) ? wsum[lane] : 0;
        #pragma unroll
        for (int o = 1; o < 8; o <<= 1) {
            int tt = __shfl_up(ws, o, 64);
            if (lane >= o) ws += tt;
        }
        if (lane < 8) wsum[lane] = ws;
    }
    __syncthreads();
    int woff = (w > 0) ? wsum[w - 1] : 0;
    int excl = woff + s - v;
    int node = k * BUCKET_SIZE + t;
    if (node < N_NODES) eoff[node] = bstart + excl;
    __syncthreads();
    cnt[t] = excl;  // reuse as cursor
    __syncthreads();
    for (int i = bstart + t; i < bend; i += 512) {
        unsigned p = ebuf[i];
        int pos = atomicAdd(&cnt[p >> 16], 1);
        csr[bstart + pos] = (int)(p & 0xffffu);
    }
    if (k == NB - 1 && t == 0) eoff[N_NODES] = N_EDGES;
}

// ---------------- GIN aggregation v4: quarter-wave edge parallelism, uint4 lanes ----------------
__global__ __launch_bounds__(256) void agg_bf16(const uint4* __restrict__ h4, const int* __restrict__ eoff,
                                                const int* __restrict__ csr, uint4* __restrict__ T4) {
    int wid = (blockIdx.x * 256 + threadIdx.x) >> 6;
    int lane = threadIdx.x & 63;
    int qtr = lane >> 4;
    int ql = lane & 15;
    if (wid >= N_NODES) return;
    int lo = eoff[wid], hi = eoff[wid + 1];

    float a[8];
    #pragma unroll
    for (int k = 0; k < 8; ++k) a[k] = 0.f;

    auto acc_row = [&](uint4 w) {
        a[0] += bfbits2f(w.x & 0xffffu); a[1] += bfbits2f(w.x >> 16);
        a[2] += bfbits2f(w.y & 0xffffu); a[3] += bfbits2f(w.y >> 16);
        a[4] += bfbits2f(w.z & 0xffffu); a[5] += bfbits2f(w.z >> 16);
        a[6] += bfbits2f(w.w & 0xffffu); a[7] += bfbits2f(w.w >> 16);
    };

    if (qtr == 0) acc_row(h4[(size_t)wid * 16 + ql]);  // self term

    for (int base = lo; base < hi; base += 64) {
        int nav = hi - base;
        if (nav > 64) nav = 64;
        int jv = (base + lane < hi) ? csr[base + lane] : 0;  // one coalesced index load
        int cmin = nav >> 2;
        int cmax = (nav + 3) >> 2;   // uniform loop bounds for the whole wave
        int i = 0;
        for (; i + 3 < cmin; i += 4) {  // 16 edges in flight across the wave
            int j0 = __shfl(jv, 4 * (i + 0) + qtr, 64);
            int j1 = __shfl(jv, 4 * (i + 1) + qtr, 64);
            int j2 = __shfl(jv, 4 * (i + 2) + qtr, 64);
            int j3 = __shfl(jv, 4 * (i + 3) + qtr, 64);
            uint4 w0 = h4[(size_t)j0 * 16 + ql];
            uint4 w1 = h4[(size_t)j1 * 16 + ql];
            uint4 w2 = h4[(size_t)j2 * 16 + ql];
            uint4 w3 = h4[(size_t)j3 * 16 + ql];
            acc_row(w0); acc_row(w1); acc_row(w2); acc_row(w3);
        }
        for (; i < cmin; ++i) {
            int j = __shfl(jv, 4 * i + qtr, 64);
            acc_row(h4[(size_t)j * 16 + ql]);
        }
        for (; i < cmax; ++i) {          // partial tail: shfl BEFORE the predicate
            int epos = 4 * i + qtr;
            int j = __shfl(jv, epos, 64);
            if (epos < nav) acc_row(h4[(size_t)j * 16 + ql]);
        }
    }

    #pragma unroll
    for (int k = 0; k < 8; ++k) {
        a[k] += __shfl_down(a[k], 32, 64);
        a[k] += __shfl_down(a[k], 16, 64);
    }
    if (qtr == 0) {
        uint4 o;
        o.x = packbf2(a[0], a[1]);
        o.y = packbf2(a[2], a[3]);
        o.z = packbf2(a[4], a[5]);
        o.w = packbf2(a[6], a[7]);
        T4[(size_t)wid * 16 + ql] = o;
    }
}

// ---------------- fused layer GEMM v2: 256-row tile, 512 threads (8 waves), 96 KB LDS --------
// Zb = relu(relu(T@W1+b1)@W2+b2); Z1 round-trips through As in LDS. Halves W staging +
// barrier count per row vs the 128-row version; grid 196 <= 256 CUs -> single round.
__global__ __launch_bounds__(512) void mm_layer(const ushort_t* __restrict__ A,
                                                const ushort_t* __restrict__ W1h, const ushort_t* __restrict__ W1l,
                                                const ushort_t* __restrict__ W2h, const ushort_t* __restrict__ W2l,
                                                const float* __restrict__ b1, const float* __restrict__ b2,
                                                ushort_t* __restrict__ Zb) {
    __shared__ ushort_t As[256 * 128];   // 64 KB
    __shared__ ushort_t Ws[128 * 128];   // 32 KB
    int tid = threadIdx.x;
    int row0 = blockIdx.x * 256;
    int wave = tid >> 6, lane = tid & 63;   // wave 0..7, each owns 32 rows
    int q = lane >> 4, mn = lane & 15;

    f32x4 acc[2][8];
    #pragma unroll
    for (int t = 0; t < 2; ++t)
        #pragma unroll
        for (int n = 0; n < 8; ++n) acc[t][n] = (f32x4)(0.f);

    // stage A: 256 rows x 16 uint4-chunks = 4096 chunks, 512 thr -> 8 iters
    #pragma unroll
    for (int i = 0; i < 8; ++i) {
        int c = tid + i * 512;
        int r = c >> 4, c8 = c & 15;
        uint4 v = make_uint4(0u, 0u, 0u, 0u);
        int gr = row0 + r;
        if (gr < N_NODES) v = *(const uint4*)(A + (size_t)gr * DIM + c8 * 8);
        *(uint4*)(&As[r * 128 + (c8 ^ (r & 7)) * 8]) = v;
    }
    auto stageW = [&](const ushort_t* src) {   // 2048 chunks, 512 thr -> 4 iters
        #pragma unroll
        for (int i = 0; i < 4; ++i) {
            int c = tid + i * 512;
            int r = c >> 4, c8 = c & 15;
            uint4 v = *(const uint4*)(src + r * DIM + c8 * 8);
            *(uint4*)(&Ws[r * 128 + (c8 ^ (r & 7)) * 8]) = v;
        }
    };
    auto compute = [&]() {
        #pragma unroll
        for (int ks = 0; ks < 4; ++ks) {
            int m0 = wave * 32 + mn;
            int m1 = m0 + 16;
            frag8 a0 = *(const frag8*)&As[m0 * 128 + (((ks * 4 + q) ^ (m0 & 7)) * 8)];
            frag8 a1 = *(const frag8*)&As[m1 * 128 + (((ks * 4 + q) ^ (m1 & 7)) * 8)];
            #pragma unroll
            for (int n = 0; n < 8; ++n) {
                int nr = n * 16 + mn;
                frag8 b = *(const frag8*)&Ws[nr * 128 + (((ks * 4 + q) ^ (nr & 7)) * 8)];
                acc[0][n] = __builtin_amdgcn_mfma_f32_16x16x32_bf16(a0, b, acc[0][n], 0, 0, 0);
                acc[1][n] = __builtin_amdgcn_mfma_f32_16x16x32_bf16(a1, b, acc[1][n], 0, 0, 0);
            }
        }
    };

    // ---- GEMM 1: Z1 = relu(A@W1 + b1) ----
    stageW(W1h);
    __syncthreads(); compute(); __syncthreads();
    stageW(W1l);
    __syncthreads(); compute(); __syncthreads();

    // epilogue 1: write bf16 Z1 back into As (swizzled), reset acc
    int mloc = wave * 32;
    #pragma unroll
    for (int t = 0; t < 2; ++t) {
        #pragma unroll
        for (int n = 0; n < 8; ++n) {
            int col = n * 16 + mn;
            float bv = b1[col];
            #pragma unroll
            for (int r = 0; r < 4; ++r) {
                int rloc = mloc + t * 16 + q * 4 + r;
                float v = fmaxf(acc[t][n][r] + bv, 0.f);
                As[rloc * 128 + ((col >> 3) ^ (rloc & 7)) * 8 + (col & 7)] = bf16rne(v);
                acc[t][n][r] = 0.f;
            }
        }
    }
    __syncthreads();
    // ---- GEMM 2: Z = relu(Z1@W2 + b2) ----
    stageW(W2h);
    __syncthreads(); compute(); __syncthreads();
    stageW(W2l);
    __syncthreads(); compute();

    // epilogue 2: bf16 streaming store
    #pragma unroll
    for (int t = 0; t < 2; ++t) {
        #pragma unroll
        for (int n = 0; n < 8; ++n) {
            int col = n * 16 + mn;
            float bv = b2[col];
            #pragma unroll
            for (int r = 0; r < 4; ++r) {
                int grow = row0 + mloc + t * 16 + q * 4 + r;
                if (grow < N_NODES)
                    Zb[(size_t)grow * DIM + col] = bf16rne(fmaxf(acc[t][n][r] + bv, 0.f));
            }
        }
    }
}

// ---------------- fused GraphNorm (non-last), DIM-SPLIT: 2 blocks per graph ----------------
__global__ __launch_bounds__(1024) void gn_fused(const unsigned* __restrict__ Zb, const int* __restrict__ gstart,
                                                 const float* __restrict__ scale, const float* __restrict__ weight,
                                                 const float* __restrict__ bias,
                                                 unsigned* __restrict__ Hb) {
    __shared__ float2 sh1[1024], sh2[1024];
    __shared__ float sa[64], sb[64];
    int g = blockIdx.x >> 1, half = blockIdx.x & 1;
    int dpl = threadIdx.x & 31, rg = threadIdx.x >> 5;
    int dp = half * 32 + dpl;
    int s = gstart[g], e = gstart[g + 1];
    float2 s1 = make_float2(0.f, 0.f), s2 = make_float2(0.f, 0.f);
    for (int n = s + rg; n < e; n += 32) {
        unsigned zz = Zb[(size_t)n * 64 + dp];
        float z0 = bfbits2f(zz & 0xffffu), z1 = bfbits2f(zz >> 16);
        s1.x += z0; s1.y += z1;
        s2.x += z0 * z0; s2.y += z1 * z1;
    }
    sh1[threadIdx.x] = s1;
    sh2[threadIdx.x] = s2;
    __syncthreads();
    if (rg == 0) {
        #pragma unroll
        for (int k = 1; k < 32; ++k) {
            float2 t1 = sh1[dpl + 32 * k], t2 = sh2[dpl + 32 * k];
            s1.x += t1.x; s1.y += t1.y;
            s2.x += t2.x; s2.y += t2.y;
        }
        int cnt = e - s;
        float cf = (float)(cnt > 0 ? cnt : 1);
        int d0 = dp * 2, d1 = d0 + 1;
        float m0 = s1.x / cf, m1 = s1.y / cf;
        float ez0 = s2.x / cf, ez1 = s2.y / cf;
        float sc0 = scale[d0], sc1 = scale[d1];
        float var0 = fmaxf(ez0 - (2.0f - sc0) * sc0 * m0 * m0, 0.f);
        float var1 = fmaxf(ez1 - (2.0f - sc1) * sc1 * m1 * m1, 0.f);
        sa[dpl * 2] = m0 * sc0;
        sa[dpl * 2 + 1] = m1 * sc1;
        sb[dpl * 2] = weight[d0] / sqrtf(var0 + GN_EPS);
        sb[dpl * 2 + 1] = weight[d1] / sqrtf(var1 + GN_EPS);
    }
    __syncthreads();
    float as0 = sa[dpl * 2], bm0 = sb[dpl * 2], bi0 = bias[dp * 2];
    float as1 = sa[dpl * 2 + 1], bm1 = sb[dpl * 2 + 1], bi1 = bias[dp * 2 + 1];
    for (int n = s + rg; n < e; n += 32) {
        unsigned zz = Zb[(size_t)n * 64 + dp];
        float z0 = bfbits2f(zz & 0xffffu), z1 = bfbits2f(zz >> 16);
        float o0 = fmaxf((z0 - as0) * bm0 + bi0, 0.f);
        float o1 = fmaxf((z1 - as1) * bm1 + bi1, 0.f);
        Hb[(size_t)n * 64 + dp] = packbf2(o0, o1);
    }
}

// ---------------- last layer: GraphNorm + relu + readout + final MLP + log_softmax ----------
__global__ __launch_bounds__(1024) void gn_last(const unsigned* __restrict__ Zb, const int* __restrict__ gstart,
                                                const float* __restrict__ scale, const float* __restrict__ weight,
                                                const float* __restrict__ bias,
                                                const float* __restrict__ fw1, const float* __restrict__ fb1,
                                                const float* __restrict__ fw2, const float* __restrict__ fb2,
                                                const float* __restrict__ fw3, const float* __restrict__ fb3,
                                                float* __restrict__ out) {
    __shared__ float2 sh1[1024], sh2[1024];
    __shared__ float sa[128], sb[128];
    __shared__ float v0[128], v1[128], v2[128], lg[10];
    int g = blockIdx.x;
    int t = threadIdx.x;
    int dp = t & 63, rg = t >> 6;
    int s = gstart[g], e = gstart[g + 1];
    float2 s1 = make_float2(0.f, 0.f), s2 = make_float2(0.f, 0.f);
    for (int n = s + rg; n < e; n += 16) {
        unsigned zz = Zb[(size_t)n * 64 + dp];
        float z0 = bfbits2f(zz & 0xffffu), z1 = bfbits2f(zz >> 16);
        s1.x += z0; s1.y += z1;
        s2.x += z0 * z0; s2.y += z1 * z1;
    }
    sh1[t] = s1;
    sh2[t] = s2;
    __syncthreads();
    if (rg == 0) {
        #pragma unroll
        for (int k = 1; k < 16; ++k) {
            float2 t1 = sh1[dp + 64 * k], t2 = sh2[dp + 64 * k];
            s1.x += t1.x; s1.y += t1.y;
            s2.x += t2.x; s2.y += t2.y;
        }
        int cnt = e - s;
        float cf = (float)(cnt > 0 ? cnt : 1);
        int d0 = dp * 2, d1 = d0 + 1;
        float m0 = s1.x / cf, m1 = s1.y / cf;
        float ez0 = s2.x / cf, ez1 = s2.y / cf;
        float sc0 = scale[d0], sc1 = scale[d1];
        float var0 = fmaxf(ez0 - (2.0f - sc0) * sc0 * m0 * m0, 0.f);
        float var1 = fmaxf(ez1 - (2.0f - sc1) * sc1 * m1 * m1, 0.f);
        sa[d0] = m0 * sc0;
        sa[d1] = m1 * sc1;
        sb[d0] = weight[d0] / sqrtf(var0 + GN_EPS);
        sb[d1] = weight[d1] / sqrtf(var1 + GN_EPS);
    }
    __syncthreads();
    int d0 = dp * 2, d1 = d0 + 1;
    float as0 = sa[d0], bm0 = sb[d0], bi0 = bias[d0];
    float as1 = sa[d1], bm1 = sb[d1], bi1 = bias[d1];
    float2 rsum = make_float2(0.f, 0.f);
    for (int n = s + rg; n < e; n += 16) {
        unsigned zz = Zb[(size_t)n * 64 + dp];
        float z0 = bfbits2f(zz & 0xffffu), z1 = bfbits2f(zz >> 16);
        rsum.x += fmaxf((z0 - as0) * bm0 + bi0, 0.f);
        rsum.y += fmaxf((z1 - as1) * bm1 + bi1, 0.f);
    }
    __syncthreads();
    sh1[t] = rsum;
    __syncthreads();
    if (rg == 0) {
        #pragma unroll
        for (int k = 1; k < 16; ++k) {
            float2 t1 = sh1[dp + 64 * k];
            rsum.x += t1.x; rsum.y += t1.y;
        }
        v0[d0] = rsum.x;
        v0[d1] = rsum.y;
    }
    __syncthreads();
    if (t < 128) {
        float acc = fb1[t];
        for (int d = 0; d < 128; ++d) acc += v0[d] * fw1[d * 128 + t];
        v1[t] = fmaxf(acc, 0.f);
    }
    __syncthreads();
    if (t < 128) {
        float acc = fb2[t];
        for (int d = 0; d < 128; ++d) acc += v1[d] * fw2[d * 128 + t];
        v2[t] = fmaxf(acc, 0.f);
    }
    __syncthreads();
    if (t < 10) {
        float acc = fb3[t];
        for (int d = 0; d < 128; ++d) acc += v2[d] * fw3[d * 10 + t];
        lg[t] = acc;
    }
    __syncthreads();
    if (t < 10) {
        float m = -1e30f;
        for (int c = 0; c < 10; ++c) m = fmaxf(m, lg[c]);
        float ssum = 0.f;
        for (int c = 0; c < 10; ++c) ssum += expf(lg[c] - m);
        out[g * 10 + t] = lg[t] - m - logf(ssum);
    }
}

extern "C" void kernel_launch(void* const* d_in, const int* in_sizes, int n_in,
                              void* d_out, int out_size, void* d_ws, size_t ws_size,
                              hipStream_t stream) {
    const float* x      = (const float*)d_in[0];
    const float* gin_w1 = (const float*)d_in[1];
    const float* gin_b1 = (const float*)d_in[2];
    const float* gin_w2 = (const float*)d_in[3];
    const float* gin_b2 = (const float*)d_in[4];
    const float* gn_w   = (const float*)d_in[5];
    const float* gn_b   = (const float*)d_in[6];
    const float* gn_s   = (const float*)d_in[7];
    const float* fw1    = (const float*)d_in[8];
    const float* fb1    = (const float*)d_in[9];
    const float* fw2    = (const float*)d_in[10];
    const float* fb2    = (const float*)d_in[11];
    const float* fw3    = (const float*)d_in[12];
    const float* fb3    = (const float*)d_in[13];
    const int*   eidx   = (const int*)d_in[14];
    const int*   batch  = (const int*)d_in[15];
    float* out = (float*)d_out;

    const int* esrc = eidx;
    const int* edst = eidx + N_EDGES;

    auto align_up = [](size_t v) { return (v + 255) & ~(size_t)255; };
    char* p = (char*)d_ws;
    unsigned* Hb = (unsigned*)p;   p += align_up((size_t)N_NODES * DIM * 2);
    unsigned* Tb = (unsigned*)p;   p += align_up((size_t)N_NODES * DIM * 2);
    unsigned* Zb = (unsigned*)p;   p += align_up((size_t)N_NODES * DIM * 2);
    ushort_t* WThi = (ushort_t*)p; p += align_up((size_t)8 * DIM * DIM * 2);
    ushort_t* WTlo = (ushort_t*)p; p += align_up((size_t)8 * DIM * DIM * 2);
    int* gstart = (int*)p;         p += align_up((N_GRAPHS + 1) * 4);
    int* cnts = (int*)p;           p += align_up((size_t)NB * B_CHUNK * 4);
    int* off = (int*)p;            p += align_up(((size_t)NB * B_CHUNK + 1) * 4);
    int* bsum = (int*)p;           p += align_up(64 * 4);
    unsigned* ebuf = (unsigned*)p; p += align_up((size_t)N_EDGES * 4);
    int* eoff = (int*)p;           p += align_up((N_NODES + 1) * 4);
    int* csr = (int*)p;            p += align_up((size_t)N_EDGES * 4);

    const int SCAN_N = NB * B_CHUNK;                      // 25088
    const int SCAN_BLKS = (SCAN_N + 1023) / 1024;         // 25 (<= 64 for scan_add butterfly)
    setup_misc<<<SETUP_BLKS, 256, 0, stream>>>(x, Hb, gin_w1, gin_w2, WThi, WTlo,
                                               batch, gstart, edst, cnts);
    scan_local<<<SCAN_BLKS, 1024, 0, stream>>>(cnts, off, bsum, SCAN_N);
    scan_add<<<SCAN_BLKS, 1024, 0, stream>>>(off, bsum, SCAN_N, N_EDGES);
    p3_place<<<B_CHUNK, 256, 0, stream>>>(esrc, edst, off, ebuf);
    p4_csr<<<NB, 512, 0, stream>>>(ebuf, off, eoff, csr);

    const int mm_grid = (N_NODES + 255) / 256;  // 196 blocks <= 256 CUs
    for (int l = 0; l < N_LAYERS; ++l) {
        agg_bf16<<<(N_NODES + 3) / 4, 256, 0, stream>>>((const uint4*)Hb, eoff, csr, (uint4*)Tb);
        mm_layer<<<mm_grid, 512, 0, stream>>>((const ushort_t*)Tb,
            WThi + (size_t)(2 * l) * DIM * DIM, WTlo + (size_t)(2 * l) * DIM * DIM,
            WThi + (size_t)(2 * l + 1) * DIM * DIM, WTlo + (size_t)(2 * l + 1) * DIM * DIM,
            gin_b1 + l * DIM, gin_b2 + l * DIM, (ushort_t*)Zb);
        if (l == N_LAYERS - 1)
            gn_last<<<N_GRAPHS, 1024, 0, stream>>>(Zb, gstart, gn_s + l * DIM,
                gn_w + l * DIM, gn_b + l * DIM, fw1, fb1, fw2, fb2, fw3, fb3, out);
        else
            gn_fused<<<N_GRAPHS * 2, 1024, 0, stream>>>(Zb, gstart, gn_s + l * DIM,
                gn_w + l * DIM, gn_b + l * DIM, Hb);
    }
}